// Round 13
// baseline (552.342 us; speedup 1.0000x reference)
//
#include <hip/hip_runtime.h>
#include <cstdint>
#include <cstddef>

#define CDIV(a,b) (((a)+(b)-1)/(b))

constexpr int N_ = 100000;
constexpr int E_ = 600000;
constexpr int D_ = 128;
constexpr int G_ = 2048;
constexpr int NHID_ = 512;
constexpr int NOUT_ = 768;
constexpr float EPS_ = 1e-5f;
constexpr int AGG_BLOCKS = 2048;

typedef short bf16x8 __attribute__((ext_vector_type(8)));
typedef float f32x4 __attribute__((ext_vector_type(4)));

__device__ __forceinline__ float wave_sum(float v){
#pragma unroll
  for (int m = 32; m; m >>= 1) v += __shfl_xor(v, m, 64);
  return v;
}
__device__ __forceinline__ float lrelu02(float v){ return v > 0.f ? v : 0.2f * v; }
__device__ __forceinline__ unsigned short f2bf(float f){
  unsigned u = __float_as_uint(f);
  u += 0x7FFF + ((u >> 16) & 1);
  return (unsigned short)(u >> 16);
}
__device__ __forceinline__ float bflo(unsigned u){ return __uint_as_float(u << 16); }
__device__ __forceinline__ float bfhi(unsigned u){ return __uint_as_float(u & 0xFFFF0000u); }

__device__ __forceinline__ float4 unplo(uint4 u){ return make_float4(bflo(u.x), bflo(u.y), bflo(u.z), bflo(u.w)); }
__device__ __forceinline__ float4 unphi(uint4 u){ return make_float4(bfhi(u.x), bfhi(u.y), bfhi(u.z), bfhi(u.w)); }
__device__ __forceinline__ float4 bnrelu4(float4 v, float4 sc, float4 sh){
  return make_float4(fmaxf(v.x*sc.x+sh.x, 0.f), fmaxf(v.y*sc.y+sh.y, 0.f),
                     fmaxf(v.z*sc.z+sh.z, 0.f), fmaxf(v.w*sc.w+sh.w, 0.f));
}
__device__ __forceinline__ float4 add4(float4 a, float4 b){
  return make_float4(a.x+b.x, a.y+b.y, a.z+b.z, a.w+b.w);
}
__device__ __forceinline__ uint4 pk4(float4 lo, float4 hi){
  uint4 u;
  u.x = (unsigned)f2bf(lo.x) | ((unsigned)f2bf(hi.x) << 16);
  u.y = (unsigned)f2bf(lo.y) | ((unsigned)f2bf(hi.y) << 16);
  u.z = (unsigned)f2bf(lo.z) | ((unsigned)f2bf(hi.z) << 16);
  u.w = (unsigned)f2bf(lo.w) | ((unsigned)f2bf(hi.w) << 16);
  return u;
}
__device__ __forceinline__ bf16x8 mkaf(float4 lo, float4 hi){
  bf16x8 a;
  a[0]=(short)f2bf(lo.x); a[1]=(short)f2bf(lo.y); a[2]=(short)f2bf(lo.z); a[3]=(short)f2bf(lo.w);
  a[4]=(short)f2bf(hi.x); a[5]=(short)f2bf(hi.y); a[6]=(short)f2bf(hi.z); a[7]=(short)f2bf(hi.w);
  return a;
}
__device__ __forceinline__ bf16x8 mkaf_u(uint4 u){
  bf16x8 a;
  a[0]=(short)(u.x & 0xFFFF); a[4]=(short)(u.x >> 16);
  a[1]=(short)(u.y & 0xFFFF); a[5]=(short)(u.y >> 16);
  a[2]=(short)(u.z & 0xFFFF); a[6]=(short)(u.z >> 16);
  a[3]=(short)(u.w & 0xFFFF); a[7]=(short)(u.w >> 16);
  return a;
}

// ---------------- CSR build ----------------
__global__ void k_count(const int* __restrict__ dst, int* __restrict__ cnt){
  int e = blockIdx.x * 256 + threadIdx.x;
  if (e < E_) atomicAdd(&cnt[dst[e]], 1);
}

__global__ void k_scan1(const int* __restrict__ cnt, int* __restrict__ ro, int* __restrict__ bs,
                        float* __restrict__ dinv){
  __shared__ int s[256];
  int tid = threadIdx.x;
  int i = blockIdx.x * 256 + tid;
  int v = (i < N_) ? cnt[i] : 0;
  s[tid] = v; __syncthreads();
  for (int off = 1; off < 256; off <<= 1){
    int add = (tid >= off) ? s[tid - off] : 0;
    __syncthreads();
    s[tid] += add;
    __syncthreads();
  }
  if (i < N_){
    ro[i] = s[tid] - v;
    dinv[i] = rsqrtf((float)(v + 1));
  }
  if (tid == 255) bs[blockIdx.x] = s[255];
}

__global__ void k_scan2(int* __restrict__ bs, int nb){
  __shared__ int s[512];
  int t = threadIdx.x;
  int v = (t < nb) ? bs[t] : 0;
  s[t] = v; __syncthreads();
  for (int off = 1; off < 512; off <<= 1){
    int a = (t >= off) ? s[t - off] : 0;
    __syncthreads();
    s[t] += a;
    __syncthreads();
  }
  if (t < nb) bs[t] = s[t] - v;
}

__global__ void k_scan3(int* __restrict__ ro, const int* __restrict__ bs){
  int i = blockIdx.x * 256 + threadIdx.x;
  if (i < N_) ro[i] += bs[i >> 8];
  if (i == N_) ro[N_] = E_;
}

__global__ void k_fill(const int* __restrict__ src, const int* __restrict__ dst,
                       const int* __restrict__ ro, int* __restrict__ cur, int* __restrict__ csr){
  int e = blockIdx.x * 256 + threadIdx.x;
  if (e < E_){
    int d = dst[e];
    int p = atomicAdd(&cur[d], 1);
    csr[ro[d] + p] = src[e];
  }
}

__global__ void k_bounds(const int* __restrict__ batch, int* __restrict__ gs){
  int g = blockIdx.x * 256 + threadIdx.x;
  if (g > G_) return;
  int lo = 0, hi = N_;
  while (lo < hi){ int mid = (lo + hi) >> 1; if (batch[mid] < g) lo = mid + 1; else hi = mid; }
  gs[g] = lo;
}

// ---------------- batched W prep ----------------
struct WprepArgs {
  const float* W[8];
  short* Wt[8];
  int K[8];
  int N[8];
  int ofs[9];
};

__global__ void k_wprep_all(WprepArgs a){
  int i = blockIdx.x * 256 + threadIdx.x;
  if (i >= a.ofs[8]) return;
  int m = 0;
  while (i >= a.ofs[m + 1]) ++m;
  int li = i - a.ofs[m];
  int K = a.K[m], Nn = a.N[m];
  int KT = K >> 5;
  int g = li & 3, t = (li >> 2) % KT, c = li / (KT * 4);
  short* o = a.Wt[m] + (size_t)li * 8;
  const float* W = a.W[m];
#pragma unroll
  for (int j = 0; j < 8; ++j){
    int k = t * 32 + (j >> 2) * 16 + g * 4 + (j & 3);
    o[j] = (short)f2bf(W[(size_t)k * Nn + c]);
  }
}

// ---------------- MFMA node matmul, 2 tiles/wave, optional column split ----------------
// JN = output col-groups of 16 per wave (8 = full 128 cols, 4 = half; blockIdx.y selects half)
// NOTE: when split (JN<8), resin and xnew MUST be different buffers (cross-block race otherwise).
template<bool XB, bool RB, int JN>
__global__ __launch_bounds__(256) void k_mm_mfma(const void* __restrict__ Xin,
                                                 const short* __restrict__ Wt,
                                                 unsigned* __restrict__ hout,
                                                 const float* __restrict__ ss,
                                                 const void* __restrict__ resin,
                                                 unsigned* __restrict__ xnew,
                                                 const float* __restrict__ prescale,
                                                 const float* __restrict__ asrc,
                                                 const float* __restrict__ adst,
                                                 float* __restrict__ al_out,
                                                 float* __restrict__ ar_out){
  int lane = threadIdx.x & 63, wid = threadIdx.x >> 6;
  int cl = lane & 15, g = lane >> 4;
  int cbase = blockIdx.y * (JN * 16);
  int r0a = blockIdx.x * 128 + wid * 16;
  int r0b = r0a + 64;
  int rowa = r0a + cl, rowb = r0b + cl;
  bool va_ = rowa < N_, vb_ = rowb < N_;
  int rma = va_ ? rowa : 0;
  int rmb = vb_ ? rowb : 0;
  bool has_res = resin != nullptr;

  uint4 xua[4], xub[4];
  float4 xfa[8], xfb[8];
  uint4 rua[4], rub[4];
  float4 rfa[8], rfb[8];
  if (XB){
    const uint4* Xa = (const uint4*)((const unsigned*)Xin + (size_t)rma * 64);
    const uint4* Xb = (const uint4*)((const unsigned*)Xin + (size_t)rmb * 64);
#pragma unroll
    for (int t = 0; t < 4; ++t){ xua[t] = Xa[t*4 + g]; xub[t] = Xb[t*4 + g]; }
  } else {
    const float4* Xa = (const float4*)((const float*)Xin + (size_t)rma * 128);
    const float4* Xb = (const float4*)((const float*)Xin + (size_t)rmb * 128);
#pragma unroll
    for (int t = 0; t < 4; ++t){
      xfa[2*t] = Xa[t*8 + g]; xfa[2*t+1] = Xa[t*8 + g + 4];
      xfb[2*t] = Xb[t*8 + g]; xfb[2*t+1] = Xb[t*8 + g + 4];
    }
  }
  if (has_res){
    if (RB){
      const uint4* Ra = (const uint4*)((const unsigned*)resin + (size_t)rma * 64);
      const uint4* Rb = (const uint4*)((const unsigned*)resin + (size_t)rmb * 64);
#pragma unroll
      for (int t = 0; t < 4; ++t){ rua[t] = Ra[t*4 + g]; rub[t] = Rb[t*4 + g]; }
    } else {
      const float4* Ra = (const float4*)((const float*)resin + (size_t)rma * 128);
      const float4* Rb = (const float4*)((const float*)resin + (size_t)rmb * 128);
#pragma unroll
      for (int t = 0; t < 4; ++t){
        rfa[2*t] = Ra[t*8 + g]; rfa[2*t+1] = Ra[t*8 + g + 4];
        rfb[2*t] = Rb[t*8 + g]; rfb[2*t+1] = Rb[t*8 + g + 4];
      }
    }
  }
  __builtin_amdgcn_sched_barrier(0);

  bf16x8 afa[4], afb[4];
#pragma unroll
  for (int t = 0; t < 4; ++t){
    float4 la, ha, lb, hb;
    if (XB){
      la = unplo(xua[t]); ha = unphi(xua[t]);
      lb = unplo(xub[t]); hb = unphi(xub[t]);
    } else {
      la = xfa[2*t]; ha = xfa[2*t+1];
      lb = xfb[2*t]; hb = xfb[2*t+1];
    }
    if (ss){
      int f0 = t * 32 + g * 4;
      float4 sc0 = *(const float4*)&ss[f0],      sh0 = *(const float4*)&ss[128 + f0];
      float4 sc1 = *(const float4*)&ss[f0 + 16], sh1 = *(const float4*)&ss[128 + f0 + 16];
      la = bnrelu4(la, sc0, sh0); ha = bnrelu4(ha, sc1, sh1);
      lb = bnrelu4(lb, sc0, sh0); hb = bnrelu4(hb, sc1, sh1);
      if (has_res){
        if (RB){
          la = add4(la, unplo(rua[t])); ha = add4(ha, unphi(rua[t]));
          lb = add4(lb, unplo(rub[t])); hb = add4(hb, unphi(rub[t]));
        } else {
          la = add4(la, rfa[2*t]); ha = add4(ha, rfa[2*t+1]);
          lb = add4(lb, rfb[2*t]); hb = add4(hb, rfb[2*t+1]);
        }
      }
      if (xnew && (JN == 8 || blockIdx.y == 0)){
        if (va_) *(uint4*)(xnew + (size_t)rowa * 64 + t*16 + g*4) = pk4(la, ha);
        if (vb_) *(uint4*)(xnew + (size_t)rowb * 64 + t*16 + g*4) = pk4(lb, hb);
      }
    }
    afa[t] = mkaf(la, ha);
    afb[t] = mkaf(lb, hb);
  }

  f32x4 accA[JN], accB[JN];
#pragma unroll
  for (int j = 0; j < JN; ++j){ accA[j] = (f32x4){0,0,0,0}; accB[j] = (f32x4){0,0,0,0}; }
#pragma unroll
  for (int t = 0; t < 4; ++t){
#pragma unroll
    for (int j = 0; j < JN; ++j){
      int c = cbase + j * 16 + cl;
      bf16x8 bf = *(const bf16x8*)(Wt + ((size_t)c * 16 + t * 4 + g) * 8);
      accA[j] = __builtin_amdgcn_mfma_f32_16x16x32_bf16(afa[t], bf, accA[j], 0, 0, 0);
      accB[j] = __builtin_amdgcn_mfma_f32_16x16x32_bf16(afb[t], bf, accB[j], 0, 0, 0);
    }
  }

  int qbase = blockIdx.y * (JN / 2);
#pragma unroll
  for (int r = 0; r < 4; ++r){
    int ra = r0a + g * 4 + r;
    if (ra < N_){
      float psc = prescale ? prescale[ra] : 1.f;
#pragma unroll
      for (int jp = 0; jp < JN/2; ++jp){
        unsigned lo = f2bf(accA[2*jp][r] * psc);
        unsigned hi = f2bf(accA[2*jp+1][r] * psc);
        hout[(size_t)ra * 64 + (qbase + jp) * 16 + cl] = (hi << 16) | lo;
      }
    }
    int rb = r0b + g * 4 + r;
    if (rb < N_){
      float psc = prescale ? prescale[rb] : 1.f;
#pragma unroll
      for (int jp = 0; jp < JN/2; ++jp){
        unsigned lo = f2bf(accB[2*jp][r] * psc);
        unsigned hi = f2bf(accB[2*jp+1][r] * psc);
        hout[(size_t)rb * 64 + (qbase + jp) * 16 + cl] = (hi << 16) | lo;
      }
    }
  }

  if (JN == 8 && al_out){
    float pal[8] = {0,0,0,0,0,0,0,0}, par[8] = {0,0,0,0,0,0,0,0};
#pragma unroll
    for (int j = 0; j < JN; ++j){
      float as_ = asrc[j * 16 + cl], ad_ = adst[j * 16 + cl];
#pragma unroll
      for (int r = 0; r < 4; ++r){
        pal[r]   += accA[j][r] * as_; par[r]   += accA[j][r] * ad_;
        pal[4+r] += accB[j][r] * as_; par[4+r] += accB[j][r] * ad_;
      }
    }
#pragma unroll
    for (int m = 1; m < 16; m <<= 1)
#pragma unroll
      for (int r = 0; r < 8; ++r){
        pal[r] += __shfl_xor(pal[r], m, 64);
        par[r] += __shfl_xor(par[r], m, 64);
      }
    if (cl == 0){
#pragma unroll
      for (int r = 0; r < 4; ++r){
        int ra = r0a + g * 4 + r;
        if (ra < N_){ al_out[ra] = pal[r]; ar_out[ra] = par[r]; }
        int rb = r0b + g * 4 + r;
        if (rb < N_){ al_out[rb] = pal[4+r]; ar_out[rb] = par[4+r]; }
      }
    }
  }
}

// ---------------- GCN aggregate (stats -> pbuf) ----------------
__global__ __launch_bounds__(256) void k_gcn_agg2(const unsigned* __restrict__ hbf, const int* __restrict__ ro,
                          const int* __restrict__ csr, const float* __restrict__ dinv,
                          const float* __restrict__ bias, unsigned* __restrict__ outb,
                          float4* __restrict__ pbuf){
  int wid = threadIdx.x >> 6, lane = threadIdx.x & 63;
  int f0 = 32 * (lane >> 4) + (lane & 15), f1 = f0 + 16;
  float bb0 = bias[f0], bb1 = bias[f1];
  float S0 = 0.f, S1 = 0.f, Q0 = 0.f, Q1 = 0.f;
  for (int node = blockIdx.x * 4 + wid; node < N_; node += AGG_BLOCKS * 4){
    int s0 = ro[node], s1 = ro[node + 1];
    int deg = s1 - s0;
    float di = dinv[node];
    unsigned us = hbf[(size_t)node * 64 + lane];
    float a0 = bflo(us), a1 = bfhi(us);
    if (deg <= 64){
      int sidx = (lane < deg) ? csr[s0 + lane] : 0;
      int j = 0;
      for (; j + 4 <= deg; j += 4){
        int sa = __shfl(sidx, j, 64),   sb = __shfl(sidx, j+1, 64);
        int sc = __shfl(sidx, j+2, 64), sd = __shfl(sidx, j+3, 64);
        unsigned ua = hbf[(size_t)sa*64+lane], ub = hbf[(size_t)sb*64+lane];
        unsigned uc = hbf[(size_t)sc*64+lane], ud = hbf[(size_t)sd*64+lane];
        a0 += bflo(ua) + bflo(ub) + bflo(uc) + bflo(ud);
        a1 += bfhi(ua) + bfhi(ub) + bfhi(uc) + bfhi(ud);
      }
      for (; j < deg; ++j){
        int s = __shfl(sidx, j, 64);
        unsigned u = hbf[(size_t)s*64+lane];
        a0 += bflo(u); a1 += bfhi(u);
      }
    } else {
      for (int base = s0; base < s1; base += 64){
        int c = min(64, s1 - base);
        int sidx = (lane < c) ? csr[base + lane] : 0;
        for (int j = 0; j < c; ++j){
          int s = __shfl(sidx, j, 64);
          unsigned u = hbf[(size_t)s*64+lane];
          a0 += bflo(u); a1 += bfhi(u);
        }
      }
    }
    float o0 = di * a0 + bb0;
    float o1 = di * a1 + bb1;
    outb[(size_t)node * 64 + lane] = (unsigned)f2bf(o0) | ((unsigned)f2bf(o1) << 16);
    S0 += o0; S1 += o1; Q0 += o0*o0; Q1 += o1*o1;
  }
  __shared__ float4 sred[4][64];
  sred[wid][lane] = make_float4(S0, S1, Q0, Q1);
  __syncthreads();
  if (wid == 0){
    float4 t = sred[0][lane];
    float4 u1 = sred[1][lane], u2 = sred[2][lane], u3 = sred[3][lane];
    t.x += u1.x + u2.x + u3.x;
    t.y += u1.y + u2.y + u3.y;
    t.z += u1.z + u2.z + u3.z;
    t.w += u1.w + u2.w + u3.w;
    pbuf[(size_t)blockIdx.x * 64 + lane] = t;
  }
}

// ---------------- GAT aggregate (stats -> pbuf) ----------------
__global__ __launch_bounds__(256) void k_gat_agg2(const unsigned* __restrict__ hbf, const int* __restrict__ ro,
                          const int* __restrict__ csr, const float* __restrict__ al,
                          const float* __restrict__ ar, const float* __restrict__ bias,
                          unsigned* __restrict__ outb, float4* __restrict__ pbuf){
  int wid = threadIdx.x >> 6, lane = threadIdx.x & 63;
  int f0 = 32 * (lane >> 4) + (lane & 15), f1 = f0 + 16;
  float bb0 = bias[f0], bb1 = bias[f1];
  float S0 = 0.f, S1 = 0.f, Q0 = 0.f, Q1 = 0.f;
  for (int node = blockIdx.x * 4 + wid; node < N_; node += AGG_BLOCKS * 4){
    int s0 = ro[node], s1 = ro[node + 1];
    int deg = s1 - s0;
    float ari = ar[node], ali = al[node];
    float pself = __expf(lrelu02(ali + ari));
    unsigned uself = hbf[(size_t)node * 64 + lane];
    float h0 = bflo(uself), h1 = bfhi(uself);
    float a0, a1;
    if (deg <= 64){
      int sidx = 0; float p = 0.f;
      if (lane < deg){ sidx = csr[s0 + lane]; p = __expf(lrelu02(al[sidx] + ari)); }
      float invd = 1.f / (wave_sum(p) + pself);
      float wl = p * invd;
      float wsf = pself * invd;
      a0 = wsf * h0; a1 = wsf * h1;
      int j = 0;
      for (; j + 4 <= deg; j += 4){
        int sa = __shfl(sidx, j, 64),   sb = __shfl(sidx, j+1, 64);
        int sc = __shfl(sidx, j+2, 64), sd = __shfl(sidx, j+3, 64);
        float wa = __shfl(wl, j, 64),   wb = __shfl(wl, j+1, 64);
        float wc = __shfl(wl, j+2, 64), wd = __shfl(wl, j+3, 64);
        unsigned ua = hbf[(size_t)sa*64+lane], ub = hbf[(size_t)sb*64+lane];
        unsigned uc = hbf[(size_t)sc*64+lane], ud = hbf[(size_t)sd*64+lane];
        a0 += wa*bflo(ua) + wb*bflo(ub) + wc*bflo(uc) + wd*bflo(ud);
        a1 += wa*bfhi(ua) + wb*bfhi(ub) + wc*bfhi(uc) + wd*bfhi(ud);
      }
      for (; j < deg; ++j){
        int s = __shfl(sidx, j, 64); float w = __shfl(wl, j, 64);
        unsigned u = hbf[(size_t)s*64+lane];
        a0 += w*bflo(u); a1 += w*bfhi(u);
      }
    } else {
      float denom = pself;
      for (int base = s0; base < s1; base += 64){
        int c = min(64, s1 - base);
        float p = 0.f;
        if (lane < c) p = __expf(lrelu02(al[csr[base + lane]] + ari));
        denom += wave_sum(p);
      }
      float invd = 1.f / denom;
      float wsf = pself * invd;
      a0 = wsf * h0; a1 = wsf * h1;
      for (int base = s0; base < s1; base += 64){
        int c = min(64, s1 - base);
        int sidx = 0; float wl = 0.f;
        if (lane < c){ sidx = csr[base + lane]; wl = __expf(lrelu02(al[sidx] + ari)) * invd; }
        for (int j = 0; j < c; ++j){
          int s = __shfl(sidx, j, 64); float w = __shfl(wl, j, 64);
          unsigned u = hbf[(size_t)s*64+lane];
          a0 += w*bflo(u); a1 += w*bfhi(u);
        }
      }
    }
    float o0 = a0 + bb0, o1 = a1 + bb1;
    outb[(size_t)node * 64 + lane] = (unsigned)f2bf(o0) | ((unsigned)f2bf(o1) << 16);
    S0 += o0; S1 += o1; Q0 += o0*o0; Q1 += o1*o1;
  }
  __shared__ float4 sred[4][64];
  sred[wid][lane] = make_float4(S0, S1, Q0, Q1);
  __syncthreads();
  if (wid == 0){
    float4 t = sred[0][lane];
    float4 u1 = sred[1][lane], u2 = sred[2][lane], u3 = sred[3][lane];
    t.x += u1.x + u2.x + u3.x;
    t.y += u1.y + u2.y + u3.y;
    t.z += u1.z + u2.z + u3.z;
    t.w += u1.w + u2.w + u3.w;
    pbuf[(size_t)blockIdx.x * 64 + lane] = t;
  }
}

// ---------------- BN partial reduce ----------------
__global__ void k_bn_reduce(const float4* __restrict__ pbuf, const float* __restrict__ g,
                            const float* __restrict__ be, float* __restrict__ ss){
  int c = blockIdx.x;
  int f0 = 32 * (c >> 4) + (c & 15), f1 = f0 + 16;
  float4 a = make_float4(0.f, 0.f, 0.f, 0.f);
  for (int r = threadIdx.x; r < AGG_BLOCKS; r += 256){
    float4 v = pbuf[(size_t)r * 64 + c];
    a.x += v.x; a.y += v.y; a.z += v.z; a.w += v.w;
  }
  __shared__ float4 s[256];
  s[threadIdx.x] = a; __syncthreads();
  for (int off = 128; off; off >>= 1){
    if (threadIdx.x < off){
      float4 o = s[threadIdx.x + off];
      s[threadIdx.x].x += o.x; s[threadIdx.x].y += o.y;
      s[threadIdx.x].z += o.z; s[threadIdx.x].w += o.w;
    }
    __syncthreads();
  }
  if (threadIdx.x == 0){
    float4 t = s[0];
    float inv_n = 1.f / (float)N_;
    float mean0 = t.x * inv_n, mean1 = t.y * inv_n;
    float var0 = fmaxf(t.z * inv_n - mean0 * mean0, 0.f);
    float var1 = fmaxf(t.w * inv_n - mean1 * mean1, 0.f);
    float sc0 = g[f0] * rsqrtf(var0 + EPS_);
    float sc1 = g[f1] * rsqrtf(var1 + EPS_);
    ss[f0] = sc0; ss[f1] = sc1;
    ss[128 + f0] = be[f0] - mean0 * sc0;
    ss[128 + f1] = be[f1] - mean1 * sc1;
  }
}

// ---------------- pool ----------------
__global__ void k_pool2(const unsigned* __restrict__ xn, const int* __restrict__ gs,
                        const float* __restrict__ ss, unsigned* __restrict__ pooled){
  int g = blockIdx.x, f = threadIdx.x & 127, half = threadIdx.x >> 7;
  int idx = ((f >> 5) << 4) | (f & 15);
  int hi = (f >> 4) & 1;
  int s = gs[g], e = gs[g + 1];
  float sc = ss[f], sh = ss[128 + f];
  float a = 0.f;
  for (int n = s + half; n < e; n += 2){
    unsigned u = xn[(size_t)n * 64 + idx];
    float v = hi ? bfhi(u) : bflo(u);
    a += fmaxf(v * sc + sh, 0.f);
  }
  __shared__ float red[256];
  red[threadIdx.x] = a; __syncthreads();
  if (half == 0 && hi == 0){
    float vlo = red[f] + red[f + 128];
    float vhi = red[f + 16] + red[f + 16 + 128];
    pooled[(size_t)g * 64 + idx] = (unsigned)f2bf(vlo) | ((unsigned)f2bf(vhi) << 16);
  }
}

// ---------------- MFMA MLP GEMM ----------------
template<int K, bool RELU, bool OUTF32>
__global__ __launch_bounds__(256) void k_gemm_mfma(const unsigned* __restrict__ A,
                                                   const short* __restrict__ Wt,
                                                   const float* __restrict__ bias,
                                                   void* __restrict__ Cout, int Ncols){
  constexpr int KT = K >> 5;
  int lane = threadIdx.x & 63, wid = threadIdx.x >> 6;
  int cl = lane & 15, g = lane >> 4;
  int row0 = blockIdx.y * 64 + wid * 16;
  int cb = blockIdx.x;
  int arow = row0 + cl;
  const uint4* Ar = (const uint4*)(A + (size_t)arow * (K / 2));

  f32x4 acc[8];
#pragma unroll
  for (int j = 0; j < 8; ++j) acc[j] = (f32x4){0,0,0,0};

  for (int t = 0; t < KT; ++t){
    bf16x8 af = mkaf_u(Ar[t*4 + g]);
#pragma unroll
    for (int j = 0; j < 8; ++j){
      int c = cb * 128 + j * 16 + cl;
      bf16x8 bf = *(const bf16x8*)(Wt + (((size_t)c * KT + t) * 4 + g) * 8);
      acc[j] = __builtin_amdgcn_mfma_f32_16x16x32_bf16(af, bf, acc[j], 0, 0, 0);
    }
  }

  if (OUTF32){
    float* C = (float*)Cout;
#pragma unroll
    for (int r = 0; r < 4; ++r){
      int row = row0 + g * 4 + r;
#pragma unroll
      for (int j = 0; j < 8; ++j){
        int c = cb * 128 + j * 16 + cl;
        float v = acc[j][r] + bias[c];
        if (RELU) v = fmaxf(v, 0.f);
        C[(size_t)row * Ncols + c] = v;
      }
    }
  } else {
    unsigned* C = (unsigned*)Cout;
#pragma unroll
    for (int r = 0; r < 4; ++r){
      int row = row0 + g * 4 + r;
#pragma unroll
      for (int jp = 0; jp < 4; ++jp){
        int clo = cb * 128 + jp * 32 + cl;
        float vlo = acc[2*jp][r] + bias[clo];
        float vhi = acc[2*jp+1][r] + bias[clo + 16];
        if (RELU){ vlo = fmaxf(vlo, 0.f); vhi = fmaxf(vhi, 0.f); }
        C[(size_t)row * (Ncols / 2) + (cb * 4 + jp) * 16 + cl] =
            (unsigned)f2bf(vlo) | ((unsigned)f2bf(vhi) << 16);
      }
    }
  }
}

// ---------------- final layernorm ----------------
__global__ void k_layernorm(const float* __restrict__ xin, const float* __restrict__ g,
                            const float* __restrict__ b, float* __restrict__ out){
  __shared__ float red[8];
  int row = blockIdx.x, tid = threadIdx.x;
  float v0 = xin[(size_t)row*768 + tid];
  float v1 = xin[(size_t)row*768 + tid + 256];
  float v2 = xin[(size_t)row*768 + tid + 512];
  float s = v0 + v1 + v2;
  float q = v0*v0 + v1*v1 + v2*v2;
  s = wave_sum(s); q = wave_sum(q);
  int wid = tid >> 6;
  if ((tid & 63) == 0){ red[wid] = s; red[4 + wid] = q; }
  __syncthreads();
  if (tid == 0){
    float ts = red[0] + red[1] + red[2] + red[3];
    float tq = red[4] + red[5] + red[6] + red[7];
    float mean = ts / 768.f;
    float var = tq / 768.f - mean * mean;
    red[0] = mean; red[1] = rsqrtf(fmaxf(var, 0.f) + EPS_);
  }
  __syncthreads();
  float mean = red[0], inv = red[1];
  out[(size_t)row*768 + tid]       = (v0 - mean) * inv * g[tid]       + b[tid];
  out[(size_t)row*768 + tid + 256] = (v1 - mean) * inv * g[tid + 256] + b[tid + 256];
  out[(size_t)row*768 + tid + 512] = (v2 - mean) * inv * g[tid + 512] + b[tid + 512];
}

extern "C" void kernel_launch(void* const* d_in, const int* in_sizes, int n_in,
                              void* d_out, int out_size, void* d_ws, size_t ws_size,
                              hipStream_t stream){
  const float* x     = (const float*)d_in[0];
  const int*   ei    = (const int*)d_in[1];
  const int*   src   = ei;
  const int*   dst   = ei + E_;
  const int*   batch = (const int*)d_in[2];
  const float* W1 = (const float*)d_in[3];  const float* b1 = (const float*)d_in[4];
  const float* W2 = (const float*)d_in[5];  const float* b2 = (const float*)d_in[6];
  const float* W3 = (const float*)d_in[7];  const float* b3 = (const float*)d_in[8];
  const float* Wa = (const float*)d_in[9];  const float* ba = (const float*)d_in[10];
  const float* a_src = (const float*)d_in[11]; const float* a_dst = (const float*)d_in[12];
  const float* g1 = (const float*)d_in[13]; const float* be1 = (const float*)d_in[14];
  const float* g2 = (const float*)d_in[15]; const float* be2 = (const float*)d_in[16];
  const float* g3 = (const float*)d_in[17]; const float* be3 = (const float*)d_in[18];
  const float* ga = (const float*)d_in[19]; const float* bea = (const float*)d_in[20];
  const float* Wl1 = (const float*)d_in[21]; const float* bl1 = (const float*)d_in[22];
  const float* Wl2 = (const float*)d_in[23]; const float* bl2 = (const float*)d_in[24];
  const float* Wl3 = (const float*)d_in[25]; const float* bl3 = (const float*)d_in[26];
  const float* Wl4 = (const float*)d_in[27]; const float* bl4 = (const float*)d_in[28];
  const float* gln = (const float*)d_in[29]; const float* bln = (const float*)d_in[30];
  float* out = (float*)d_out;

  char* base = (char*)d_ws;
  size_t off = 0;
  auto alloc = [&](size_t bytes)->char*{
    char* p = base + off;
    off += (bytes + 255) & ~(size_t)255;
    return p;
  };
  int*   cnt    = (int*)  alloc((size_t)N_ * 4);
  float* dinv   = (float*)alloc((size_t)N_ * 4);
  int*   ro     = (int*)  alloc((size_t)(N_ + 1) * 4);
  int*   bs     = (int*)  alloc(512 * 4);
  int*   cur    = (int*)  alloc((size_t)N_ * 4);
  int*   csr    = (int*)  alloc((size_t)E_ * 4);
  int*   gstart = (int*)  alloc((size_t)(G_ + 1) * 4);
  float* al     = (float*)alloc((size_t)N_ * 4);
  float* ar     = (float*)alloc((size_t)N_ * 4);
  float* ss     = (float*)alloc(256 * 4);
  float4* pbuf  = (float4*)alloc((size_t)AGG_BLOCKS * 64 * 16);
  short* wt1    = (short*)alloc((size_t)128 * 128 * 2);
  short* wt2    = (short*)alloc((size_t)128 * 128 * 2);
  short* wt3    = (short*)alloc((size_t)128 * 128 * 2);
  short* wta    = (short*)alloc((size_t)128 * 128 * 2);
  short* wtl1   = (short*)alloc((size_t)128 * NHID_ * 2);
  short* wtl2   = (short*)alloc((size_t)NHID_ * NHID_ * 2);
  short* wtl3   = (short*)alloc((size_t)NHID_ * NHID_ * 2);
  short* wtl4   = (short*)alloc((size_t)NHID_ * NOUT_ * 2);
  unsigned* bufH  = (unsigned*)alloc((size_t)N_ * 64 * 4);
  unsigned* bufYb = (unsigned*)alloc((size_t)N_ * 64 * 4);
  unsigned* xresA = (unsigned*)alloc((size_t)N_ * 64 * 4);
  unsigned* xresB = (unsigned*)alloc((size_t)N_ * 64 * 4);
  unsigned* pooled= (unsigned*)alloc((size_t)G_ * 64 * 4);
  unsigned* m1b   = (unsigned*)alloc((size_t)G_ * (NHID_/2) * 4);
  unsigned* m2b   = (unsigned*)alloc((size_t)G_ * (NHID_/2) * 4);
  float* m4     = (float*)alloc((size_t)G_ * NOUT_ * 4);
  (void)ws_size; (void)in_sizes; (void)n_in; (void)out_size;

  const int nbE = CDIV(E_, 256), nbN = CDIV(N_, 256);
  const int MMB = CDIV(N_, 128);

  hipMemsetAsync(cnt, 0, (size_t)N_ * 4, stream);
  k_count<<<nbE, 256, 0, stream>>>(dst, cnt);
  k_scan1<<<nbN, 256, 0, stream>>>(cnt, ro, bs, dinv);
  k_scan2<<<1, 512, 0, stream>>>(bs, nbN);
  k_scan3<<<CDIV(N_ + 1, 256), 256, 0, stream>>>(ro, bs);
  hipMemsetAsync(cur, 0, (size_t)N_ * 4, stream);
  k_fill<<<nbE, 256, 0, stream>>>(src, dst, ro, cur, csr);
  k_bounds<<<CDIV(G_ + 1, 256), 256, 0, stream>>>(batch, gstart);

  {
    WprepArgs a;
    const float* Ws[8] = {W1, W2, W3, Wa, Wl1, Wl2, Wl3, Wl4};
    short* Wts[8] = {wt1, wt2, wt3, wta, wtl1, wtl2, wtl3, wtl4};
    int Ks[8] = {128,128,128,128, 128, NHID_, NHID_, NHID_};
    int Ns[8] = {128,128,128,128, NHID_, NHID_, NHID_, NOUT_};
    int run = 0;
    for (int m = 0; m < 8; ++m){
      a.W[m] = Ws[m]; a.Wt[m] = Wts[m]; a.K[m] = Ks[m]; a.N[m] = Ns[m];
      a.ofs[m] = run;
      run += Ns[m] * (Ks[m] >> 5) * 4;
    }
    a.ofs[8] = run;
    k_wprep_all<<<CDIV(run, 256), 256, 0, stream>>>(a);
  }

  // L1 (col-split)
  k_mm_mfma<false,false,4><<<dim3(MMB,2), 256, 0, stream>>>(x, wt1, bufH, nullptr, nullptr, nullptr,
                                                            dinv, nullptr, nullptr, nullptr, nullptr);
  k_gcn_agg2<<<AGG_BLOCKS, 256, 0, stream>>>(bufH, ro, csr, dinv, b1, bufYb, pbuf);
  k_bn_reduce<<<64, 256, 0, stream>>>(pbuf, g1, be1, ss);
  // L2 (col-split): res = x (f32, read-only), xnew = xresA
  k_mm_mfma<true,false,4><<<dim3(MMB,2), 256, 0, stream>>>(bufYb, wt2, bufH, ss, x, xresA,
                                                           dinv, nullptr, nullptr, nullptr, nullptr);
  k_gcn_agg2<<<AGG_BLOCKS, 256, 0, stream>>>(bufH, ro, csr, dinv, b2, bufYb, pbuf);
  k_bn_reduce<<<64, 256, 0, stream>>>(pbuf, g2, be2, ss);
  // L3 (col-split): res = xresA (read-only), xnew = xresB  -- ping-pong, no race
  k_mm_mfma<true,true,4><<<dim3(MMB,2), 256, 0, stream>>>(bufYb, wt3, bufH, ss, xresA, xresB,
                                                          dinv, nullptr, nullptr, nullptr, nullptr);
  k_gcn_agg2<<<AGG_BLOCKS, 256, 0, stream>>>(bufH, ro, csr, dinv, b3, bufYb, pbuf);
  k_bn_reduce<<<64, 256, 0, stream>>>(pbuf, g3, be3, ss);
  // GAT (unsplit): res = xresB
  k_mm_mfma<true,true,8><<<dim3(MMB,1), 256, 0, stream>>>(bufYb, wta, bufH, ss, xresB, nullptr,
                                                          nullptr, a_src, a_dst, al, ar);
  k_gat_agg2<<<AGG_BLOCKS, 256, 0, stream>>>(bufH, ro, csr, al, ar, ba, bufYb, pbuf);
  k_bn_reduce<<<64, 256, 0, stream>>>(pbuf, ga, bea, ss);
  // pool
  k_pool2<<<G_, 256, 0, stream>>>(bufYb, gstart, ss, pooled);
  // MLP via MFMA
  k_gemm_mfma<128, true, false><<<dim3(NHID_/128, G_/64), 256, 0, stream>>>(pooled, wtl1, bl1, m1b, NHID_);
  k_gemm_mfma<512, true, false><<<dim3(NHID_/128, G_/64), 256, 0, stream>>>(m1b, wtl2, bl2, m2b, NHID_);
  k_gemm_mfma<512, true, false><<<dim3(NHID_/128, G_/64), 256, 0, stream>>>(m2b, wtl3, bl3, m1b, NHID_);
  k_gemm_mfma<512, false, true><<<dim3(NOUT_/128, G_/64), 256, 0, stream>>>(m1b, wtl4, bl4, m4, NOUT_);
  k_layernorm<<<G_, 256, 0, stream>>>(m4, gln, bln, out);
}

// Round 14
// 549.590 us; speedup vs baseline: 1.0050x; 1.0050x over previous
//
#include <hip/hip_runtime.h>
#include <cstdint>
#include <cstddef>

#define CDIV(a,b) (((a)+(b)-1)/(b))

constexpr int N_ = 100000;
constexpr int E_ = 600000;
constexpr int D_ = 128;
constexpr int G_ = 2048;
constexpr int NHID_ = 512;
constexpr int NOUT_ = 768;
constexpr float EPS_ = 1e-5f;
constexpr int AGG_BLOCKS = 2048;

typedef short bf16x8 __attribute__((ext_vector_type(8)));
typedef float f32x4 __attribute__((ext_vector_type(4)));

__device__ __forceinline__ float wave_sum(float v){
#pragma unroll
  for (int m = 32; m; m >>= 1) v += __shfl_xor(v, m, 64);
  return v;
}
__device__ __forceinline__ float lrelu02(float v){ return v > 0.f ? v : 0.2f * v; }
__device__ __forceinline__ unsigned short f2bf(float f){
  unsigned u = __float_as_uint(f);
  u += 0x7FFF + ((u >> 16) & 1);
  return (unsigned short)(u >> 16);
}
__device__ __forceinline__ float bflo(unsigned u){ return __uint_as_float(u << 16); }
__device__ __forceinline__ float bfhi(unsigned u){ return __uint_as_float(u & 0xFFFF0000u); }

__device__ __forceinline__ float4 unplo(uint4 u){ return make_float4(bflo(u.x), bflo(u.y), bflo(u.z), bflo(u.w)); }
__device__ __forceinline__ float4 unphi(uint4 u){ return make_float4(bfhi(u.x), bfhi(u.y), bfhi(u.z), bfhi(u.w)); }
__device__ __forceinline__ float4 bnrelu4(float4 v, float4 sc, float4 sh){
  return make_float4(fmaxf(v.x*sc.x+sh.x, 0.f), fmaxf(v.y*sc.y+sh.y, 0.f),
                     fmaxf(v.z*sc.z+sh.z, 0.f), fmaxf(v.w*sc.w+sh.w, 0.f));
}
__device__ __forceinline__ float4 add4(float4 a, float4 b){
  return make_float4(a.x+b.x, a.y+b.y, a.z+b.z, a.w+b.w);
}
__device__ __forceinline__ uint4 pk4(float4 lo, float4 hi){
  uint4 u;
  u.x = (unsigned)f2bf(lo.x) | ((unsigned)f2bf(hi.x) << 16);
  u.y = (unsigned)f2bf(lo.y) | ((unsigned)f2bf(hi.y) << 16);
  u.z = (unsigned)f2bf(lo.z) | ((unsigned)f2bf(hi.z) << 16);
  u.w = (unsigned)f2bf(lo.w) | ((unsigned)f2bf(hi.w) << 16);
  return u;
}
__device__ __forceinline__ bf16x8 mkaf(float4 lo, float4 hi){
  bf16x8 a;
  a[0]=(short)f2bf(lo.x); a[1]=(short)f2bf(lo.y); a[2]=(short)f2bf(lo.z); a[3]=(short)f2bf(lo.w);
  a[4]=(short)f2bf(hi.x); a[5]=(short)f2bf(hi.y); a[6]=(short)f2bf(hi.z); a[7]=(short)f2bf(hi.w);
  return a;
}
__device__ __forceinline__ bf16x8 mkaf_u(uint4 u){
  bf16x8 a;
  a[0]=(short)(u.x & 0xFFFF); a[4]=(short)(u.x >> 16);
  a[1]=(short)(u.y & 0xFFFF); a[5]=(short)(u.y >> 16);
  a[2]=(short)(u.z & 0xFFFF); a[6]=(short)(u.z >> 16);
  a[3]=(short)(u.w & 0xFFFF); a[7]=(short)(u.w >> 16);
  return a;
}

// ---------------- CSR build ----------------
__global__ void k_count(const int* __restrict__ dst, int* __restrict__ cnt){
  int e = blockIdx.x * 256 + threadIdx.x;
  if (e < E_) atomicAdd(&cnt[dst[e]], 1);
}

__global__ void k_scan1(const int* __restrict__ cnt, int* __restrict__ ro, int* __restrict__ bs,
                        float* __restrict__ dinv){
  __shared__ int s[256];
  int tid = threadIdx.x;
  int i = blockIdx.x * 256 + tid;
  int v = (i < N_) ? cnt[i] : 0;
  s[tid] = v; __syncthreads();
  for (int off = 1; off < 256; off <<= 1){
    int add = (tid >= off) ? s[tid - off] : 0;
    __syncthreads();
    s[tid] += add;
    __syncthreads();
  }
  if (i < N_){
    ro[i] = s[tid] - v;
    dinv[i] = rsqrtf((float)(v + 1));
  }
  if (tid == 255) bs[blockIdx.x] = s[255];
}

__global__ void k_scan2(int* __restrict__ bs, int nb){
  __shared__ int s[512];
  int t = threadIdx.x;
  int v = (t < nb) ? bs[t] : 0;
  s[t] = v; __syncthreads();
  for (int off = 1; off < 512; off <<= 1){
    int a = (t >= off) ? s[t - off] : 0;
    __syncthreads();
    s[t] += a;
    __syncthreads();
  }
  if (t < nb) bs[t] = s[t] - v;
}

__global__ void k_scan3(int* __restrict__ ro, const int* __restrict__ bs){
  int i = blockIdx.x * 256 + threadIdx.x;
  if (i < N_) ro[i] += bs[i >> 8];
  if (i == N_) ro[N_] = E_;
}

__global__ void k_fill(const int* __restrict__ src, const int* __restrict__ dst,
                       const int* __restrict__ ro, int* __restrict__ cur, int* __restrict__ csr){
  int e = blockIdx.x * 256 + threadIdx.x;
  if (e < E_){
    int d = dst[e];
    int p = atomicAdd(&cur[d], 1);
    csr[ro[d] + p] = src[e];
  }
}

__global__ void k_bounds(const int* __restrict__ batch, int* __restrict__ gs){
  int g = blockIdx.x * 256 + threadIdx.x;
  if (g > G_) return;
  int lo = 0, hi = N_;
  while (lo < hi){ int mid = (lo + hi) >> 1; if (batch[mid] < g) lo = mid + 1; else hi = mid; }
  gs[g] = lo;
}

// ---------------- batched W prep ----------------
struct WprepArgs {
  const float* W[8];
  short* Wt[8];
  int K[8];
  int N[8];
  int ofs[9];
};

__global__ void k_wprep_all(WprepArgs a){
  int i = blockIdx.x * 256 + threadIdx.x;
  if (i >= a.ofs[8]) return;
  int m = 0;
  while (i >= a.ofs[m + 1]) ++m;
  int li = i - a.ofs[m];
  int K = a.K[m], Nn = a.N[m];
  int KT = K >> 5;
  int g = li & 3, t = (li >> 2) % KT, c = li / (KT * 4);
  short* o = a.Wt[m] + (size_t)li * 8;
  const float* W = a.W[m];
#pragma unroll
  for (int j = 0; j < 8; ++j){
    int k = t * 32 + (j >> 2) * 16 + g * 4 + (j & 3);
    o[j] = (short)f2bf(W[(size_t)k * Nn + c]);
  }
}

// ---------------- MFMA node matmul, 2 tiles/wave (R11-best structure) ----------------
template<bool XB, bool RB>
__global__ __launch_bounds__(256) void k_mm_mfma(const void* __restrict__ Xin,
                                                 const short* __restrict__ Wt,
                                                 unsigned* __restrict__ hout,
                                                 const float* __restrict__ ss,
                                                 const void* __restrict__ resin,
                                                 unsigned* __restrict__ xnew,
                                                 const float* __restrict__ prescale,
                                                 const float* __restrict__ asrc,
                                                 const float* __restrict__ adst,
                                                 float* __restrict__ al_out,
                                                 float* __restrict__ ar_out){
  int lane = threadIdx.x & 63, wid = threadIdx.x >> 6;
  int cl = lane & 15, g = lane >> 4;
  int r0a = blockIdx.x * 128 + wid * 16;
  int r0b = r0a + 64;
  int rowa = r0a + cl, rowb = r0b + cl;
  bool va_ = rowa < N_, vb_ = rowb < N_;
  int rma = va_ ? rowa : 0;
  int rmb = vb_ ? rowb : 0;
  bool has_res = resin != nullptr;

  uint4 xua[4], xub[4];
  float4 xfa[8], xfb[8];
  uint4 rua[4], rub[4];
  float4 rfa[8], rfb[8];
  if (XB){
    const uint4* Xa = (const uint4*)((const unsigned*)Xin + (size_t)rma * 64);
    const uint4* Xb = (const uint4*)((const unsigned*)Xin + (size_t)rmb * 64);
#pragma unroll
    for (int t = 0; t < 4; ++t){ xua[t] = Xa[t*4 + g]; xub[t] = Xb[t*4 + g]; }
  } else {
    const float4* Xa = (const float4*)((const float*)Xin + (size_t)rma * 128);
    const float4* Xb = (const float4*)((const float*)Xin + (size_t)rmb * 128);
#pragma unroll
    for (int t = 0; t < 4; ++t){
      xfa[2*t] = Xa[t*8 + g]; xfa[2*t+1] = Xa[t*8 + g + 4];
      xfb[2*t] = Xb[t*8 + g]; xfb[2*t+1] = Xb[t*8 + g + 4];
    }
  }
  if (has_res){
    if (RB){
      const uint4* Ra = (const uint4*)((const unsigned*)resin + (size_t)rma * 64);
      const uint4* Rb = (const uint4*)((const unsigned*)resin + (size_t)rmb * 64);
#pragma unroll
      for (int t = 0; t < 4; ++t){ rua[t] = Ra[t*4 + g]; rub[t] = Rb[t*4 + g]; }
    } else {
      const float4* Ra = (const float4*)((const float*)resin + (size_t)rma * 128);
      const float4* Rb = (const float4*)((const float*)resin + (size_t)rmb * 128);
#pragma unroll
      for (int t = 0; t < 4; ++t){
        rfa[2*t] = Ra[t*8 + g]; rfa[2*t+1] = Ra[t*8 + g + 4];
        rfb[2*t] = Rb[t*8 + g]; rfb[2*t+1] = Rb[t*8 + g + 4];
      }
    }
  }
  __builtin_amdgcn_sched_barrier(0);

  bf16x8 afa[4], afb[4];
#pragma unroll
  for (int t = 0; t < 4; ++t){
    float4 la, ha, lb, hb;
    if (XB){
      la = unplo(xua[t]); ha = unphi(xua[t]);
      lb = unplo(xub[t]); hb = unphi(xub[t]);
    } else {
      la = xfa[2*t]; ha = xfa[2*t+1];
      lb = xfb[2*t]; hb = xfb[2*t+1];
    }
    if (ss){
      int f0 = t * 32 + g * 4;
      float4 sc0 = *(const float4*)&ss[f0],      sh0 = *(const float4*)&ss[128 + f0];
      float4 sc1 = *(const float4*)&ss[f0 + 16], sh1 = *(const float4*)&ss[128 + f0 + 16];
      la = bnrelu4(la, sc0, sh0); ha = bnrelu4(ha, sc1, sh1);
      lb = bnrelu4(lb, sc0, sh0); hb = bnrelu4(hb, sc1, sh1);
      if (has_res){
        if (RB){
          la = add4(la, unplo(rua[t])); ha = add4(ha, unphi(rua[t]));
          lb = add4(lb, unplo(rub[t])); hb = add4(hb, unphi(rub[t]));
        } else {
          la = add4(la, rfa[2*t]); ha = add4(ha, rfa[2*t+1]);
          lb = add4(lb, rfb[2*t]); hb = add4(hb, rfb[2*t+1]);
        }
      }
      if (xnew){
        if (va_) *(uint4*)(xnew + (size_t)rowa * 64 + t*16 + g*4) = pk4(la, ha);
        if (vb_) *(uint4*)(xnew + (size_t)rowb * 64 + t*16 + g*4) = pk4(lb, hb);
      }
    }
    afa[t] = mkaf(la, ha);
    afb[t] = mkaf(lb, hb);
  }

  f32x4 accA[8], accB[8];
#pragma unroll
  for (int j = 0; j < 8; ++j){ accA[j] = (f32x4){0,0,0,0}; accB[j] = (f32x4){0,0,0,0}; }
#pragma unroll
  for (int t = 0; t < 4; ++t){
#pragma unroll
    for (int j = 0; j < 8; ++j){
      int c = j * 16 + cl;
      bf16x8 bf = *(const bf16x8*)(Wt + ((size_t)c * 16 + t * 4 + g) * 8);
      accA[j] = __builtin_amdgcn_mfma_f32_16x16x32_bf16(afa[t], bf, accA[j], 0, 0, 0);
      accB[j] = __builtin_amdgcn_mfma_f32_16x16x32_bf16(afb[t], bf, accB[j], 0, 0, 0);
    }
  }

#pragma unroll
  for (int r = 0; r < 4; ++r){
    int ra = r0a + g * 4 + r;
    if (ra < N_){
      float psc = prescale ? prescale[ra] : 1.f;
#pragma unroll
      for (int jp = 0; jp < 4; ++jp){
        unsigned lo = f2bf(accA[2*jp][r] * psc);
        unsigned hi = f2bf(accA[2*jp+1][r] * psc);
        hout[(size_t)ra * 64 + jp * 16 + cl] = (hi << 16) | lo;
      }
    }
    int rb = r0b + g * 4 + r;
    if (rb < N_){
      float psc = prescale ? prescale[rb] : 1.f;
#pragma unroll
      for (int jp = 0; jp < 4; ++jp){
        unsigned lo = f2bf(accB[2*jp][r] * psc);
        unsigned hi = f2bf(accB[2*jp+1][r] * psc);
        hout[(size_t)rb * 64 + jp * 16 + cl] = (hi << 16) | lo;
      }
    }
  }

  if (al_out){
    float pal[8] = {0,0,0,0,0,0,0,0}, par[8] = {0,0,0,0,0,0,0,0};
#pragma unroll
    for (int j = 0; j < 8; ++j){
      float as_ = asrc[j * 16 + cl], ad_ = adst[j * 16 + cl];
#pragma unroll
      for (int r = 0; r < 4; ++r){
        pal[r]   += accA[j][r] * as_; par[r]   += accA[j][r] * ad_;
        pal[4+r] += accB[j][r] * as_; par[4+r] += accB[j][r] * ad_;
      }
    }
#pragma unroll
    for (int m = 1; m < 16; m <<= 1)
#pragma unroll
      for (int r = 0; r < 8; ++r){
        pal[r] += __shfl_xor(pal[r], m, 64);
        par[r] += __shfl_xor(par[r], m, 64);
      }
    if (cl == 0){
#pragma unroll
      for (int r = 0; r < 4; ++r){
        int ra = r0a + g * 4 + r;
        if (ra < N_){ al_out[ra] = pal[r]; ar_out[ra] = par[r]; }
        int rb = r0b + g * 4 + r;
        if (rb < N_){ al_out[rb] = pal[4+r]; ar_out[rb] = par[4+r]; }
      }
    }
  }
}

// ---------------- GCN aggregate (gather unrolled x8) ----------------
__global__ __launch_bounds__(256) void k_gcn_agg2(const unsigned* __restrict__ hbf, const int* __restrict__ ro,
                          const int* __restrict__ csr, const float* __restrict__ dinv,
                          const float* __restrict__ bias, unsigned* __restrict__ outb,
                          float4* __restrict__ pbuf){
  int wid = threadIdx.x >> 6, lane = threadIdx.x & 63;
  int f0 = 32 * (lane >> 4) + (lane & 15), f1 = f0 + 16;
  float bb0 = bias[f0], bb1 = bias[f1];
  float S0 = 0.f, S1 = 0.f, Q0 = 0.f, Q1 = 0.f;
  for (int node = blockIdx.x * 4 + wid; node < N_; node += AGG_BLOCKS * 4){
    int s0 = ro[node], s1 = ro[node + 1];
    int deg = s1 - s0;
    float di = dinv[node];
    unsigned us = hbf[(size_t)node * 64 + lane];
    float a0 = bflo(us), a1 = bfhi(us);
    if (deg <= 64){
      int sidx = (lane < deg) ? csr[s0 + lane] : 0;
      int j = 0;
      for (; j + 8 <= deg; j += 8){
        unsigned u0 = hbf[(size_t)__shfl(sidx, j  , 64)*64+lane];
        unsigned u1 = hbf[(size_t)__shfl(sidx, j+1, 64)*64+lane];
        unsigned u2 = hbf[(size_t)__shfl(sidx, j+2, 64)*64+lane];
        unsigned u3 = hbf[(size_t)__shfl(sidx, j+3, 64)*64+lane];
        unsigned u4 = hbf[(size_t)__shfl(sidx, j+4, 64)*64+lane];
        unsigned u5 = hbf[(size_t)__shfl(sidx, j+5, 64)*64+lane];
        unsigned u6 = hbf[(size_t)__shfl(sidx, j+6, 64)*64+lane];
        unsigned u7 = hbf[(size_t)__shfl(sidx, j+7, 64)*64+lane];
        a0 += bflo(u0) + bflo(u1) + bflo(u2) + bflo(u3)
            + bflo(u4) + bflo(u5) + bflo(u6) + bflo(u7);
        a1 += bfhi(u0) + bfhi(u1) + bfhi(u2) + bfhi(u3)
            + bfhi(u4) + bfhi(u5) + bfhi(u6) + bfhi(u7);
      }
      for (; j < deg; ++j){
        int s = __shfl(sidx, j, 64);
        unsigned u = hbf[(size_t)s*64+lane];
        a0 += bflo(u); a1 += bfhi(u);
      }
    } else {
      for (int base = s0; base < s1; base += 64){
        int c = min(64, s1 - base);
        int sidx = (lane < c) ? csr[base + lane] : 0;
        int j = 0;
        for (; j + 8 <= c; j += 8){
          unsigned u0 = hbf[(size_t)__shfl(sidx, j  , 64)*64+lane];
          unsigned u1 = hbf[(size_t)__shfl(sidx, j+1, 64)*64+lane];
          unsigned u2 = hbf[(size_t)__shfl(sidx, j+2, 64)*64+lane];
          unsigned u3 = hbf[(size_t)__shfl(sidx, j+3, 64)*64+lane];
          unsigned u4 = hbf[(size_t)__shfl(sidx, j+4, 64)*64+lane];
          unsigned u5 = hbf[(size_t)__shfl(sidx, j+5, 64)*64+lane];
          unsigned u6 = hbf[(size_t)__shfl(sidx, j+6, 64)*64+lane];
          unsigned u7 = hbf[(size_t)__shfl(sidx, j+7, 64)*64+lane];
          a0 += bflo(u0) + bflo(u1) + bflo(u2) + bflo(u3)
              + bflo(u4) + bflo(u5) + bflo(u6) + bflo(u7);
          a1 += bfhi(u0) + bfhi(u1) + bfhi(u2) + bfhi(u3)
              + bfhi(u4) + bfhi(u5) + bfhi(u6) + bfhi(u7);
        }
        for (; j < c; ++j){
          int s = __shfl(sidx, j, 64);
          unsigned u = hbf[(size_t)s*64+lane];
          a0 += bflo(u); a1 += bfhi(u);
        }
      }
    }
    float o0 = di * a0 + bb0;
    float o1 = di * a1 + bb1;
    outb[(size_t)node * 64 + lane] = (unsigned)f2bf(o0) | ((unsigned)f2bf(o1) << 16);
    S0 += o0; S1 += o1; Q0 += o0*o0; Q1 += o1*o1;
  }
  __shared__ float4 sred[4][64];
  sred[wid][lane] = make_float4(S0, S1, Q0, Q1);
  __syncthreads();
  if (wid == 0){
    float4 t = sred[0][lane];
    float4 u1 = sred[1][lane], u2 = sred[2][lane], u3 = sred[3][lane];
    t.x += u1.x + u2.x + u3.x;
    t.y += u1.y + u2.y + u3.y;
    t.z += u1.z + u2.z + u3.z;
    t.w += u1.w + u2.w + u3.w;
    pbuf[(size_t)blockIdx.x * 64 + lane] = t;
  }
}

// ---------------- GAT aggregate (gather unrolled x8) ----------------
__global__ __launch_bounds__(256) void k_gat_agg2(const unsigned* __restrict__ hbf, const int* __restrict__ ro,
                          const int* __restrict__ csr, const float* __restrict__ al,
                          const float* __restrict__ ar, const float* __restrict__ bias,
                          unsigned* __restrict__ outb, float4* __restrict__ pbuf){
  int wid = threadIdx.x >> 6, lane = threadIdx.x & 63;
  int f0 = 32 * (lane >> 4) + (lane & 15), f1 = f0 + 16;
  float bb0 = bias[f0], bb1 = bias[f1];
  float S0 = 0.f, S1 = 0.f, Q0 = 0.f, Q1 = 0.f;
  for (int node = blockIdx.x * 4 + wid; node < N_; node += AGG_BLOCKS * 4){
    int s0 = ro[node], s1 = ro[node + 1];
    int deg = s1 - s0;
    float ari = ar[node], ali = al[node];
    float pself = __expf(lrelu02(ali + ari));
    unsigned uself = hbf[(size_t)node * 64 + lane];
    float h0 = bflo(uself), h1 = bfhi(uself);
    float a0, a1;
    if (deg <= 64){
      int sidx = 0; float p = 0.f;
      if (lane < deg){ sidx = csr[s0 + lane]; p = __expf(lrelu02(al[sidx] + ari)); }
      float invd = 1.f / (wave_sum(p) + pself);
      float wl = p * invd;
      float wsf = pself * invd;
      a0 = wsf * h0; a1 = wsf * h1;
      int j = 0;
      for (; j + 8 <= deg; j += 8){
        unsigned u0 = hbf[(size_t)__shfl(sidx, j  , 64)*64+lane];
        unsigned u1 = hbf[(size_t)__shfl(sidx, j+1, 64)*64+lane];
        unsigned u2 = hbf[(size_t)__shfl(sidx, j+2, 64)*64+lane];
        unsigned u3 = hbf[(size_t)__shfl(sidx, j+3, 64)*64+lane];
        unsigned u4 = hbf[(size_t)__shfl(sidx, j+4, 64)*64+lane];
        unsigned u5 = hbf[(size_t)__shfl(sidx, j+5, 64)*64+lane];
        unsigned u6 = hbf[(size_t)__shfl(sidx, j+6, 64)*64+lane];
        unsigned u7 = hbf[(size_t)__shfl(sidx, j+7, 64)*64+lane];
        float w0 = __shfl(wl, j  , 64), w1 = __shfl(wl, j+1, 64);
        float w2 = __shfl(wl, j+2, 64), w3 = __shfl(wl, j+3, 64);
        float w4 = __shfl(wl, j+4, 64), w5 = __shfl(wl, j+5, 64);
        float w6 = __shfl(wl, j+6, 64), w7 = __shfl(wl, j+7, 64);
        a0 += w0*bflo(u0) + w1*bflo(u1) + w2*bflo(u2) + w3*bflo(u3)
            + w4*bflo(u4) + w5*bflo(u5) + w6*bflo(u6) + w7*bflo(u7);
        a1 += w0*bfhi(u0) + w1*bfhi(u1) + w2*bfhi(u2) + w3*bfhi(u3)
            + w4*bfhi(u4) + w5*bfhi(u5) + w6*bfhi(u6) + w7*bfhi(u7);
      }
      for (; j < deg; ++j){
        int s = __shfl(sidx, j, 64); float w = __shfl(wl, j, 64);
        unsigned u = hbf[(size_t)s*64+lane];
        a0 += w*bflo(u); a1 += w*bfhi(u);
      }
    } else {
      float denom = pself;
      for (int base = s0; base < s1; base += 64){
        int c = min(64, s1 - base);
        float p = 0.f;
        if (lane < c) p = __expf(lrelu02(al[csr[base + lane]] + ari));
        denom += wave_sum(p);
      }
      float invd = 1.f / denom;
      float wsf = pself * invd;
      a0 = wsf * h0; a1 = wsf * h1;
      for (int base = s0; base < s1; base += 64){
        int c = min(64, s1 - base);
        int sidx = 0; float wl = 0.f;
        if (lane < c){ sidx = csr[base + lane]; wl = __expf(lrelu02(al[sidx] + ari)) * invd; }
        for (int j = 0; j < c; ++j){
          int s = __shfl(sidx, j, 64); float w = __shfl(wl, j, 64);
          unsigned u = hbf[(size_t)s*64+lane];
          a0 += w*bflo(u); a1 += w*bfhi(u);
        }
      }
    }
    float o0 = a0 + bb0, o1 = a1 + bb1;
    outb[(size_t)node * 64 + lane] = (unsigned)f2bf(o0) | ((unsigned)f2bf(o1) << 16);
    S0 += o0; S1 += o1; Q0 += o0*o0; Q1 += o1*o1;
  }
  __shared__ float4 sred[4][64];
  sred[wid][lane] = make_float4(S0, S1, Q0, Q1);
  __syncthreads();
  if (wid == 0){
    float4 t = sred[0][lane];
    float4 u1 = sred[1][lane], u2 = sred[2][lane], u3 = sred[3][lane];
    t.x += u1.x + u2.x + u3.x;
    t.y += u1.y + u2.y + u3.y;
    t.z += u1.z + u2.z + u3.z;
    t.w += u1.w + u2.w + u3.w;
    pbuf[(size_t)blockIdx.x * 64 + lane] = t;
  }
}

// ---------------- BN partial reduce ----------------
__global__ void k_bn_reduce(const float4* __restrict__ pbuf, const float* __restrict__ g,
                            const float* __restrict__ be, float* __restrict__ ss){
  int c = blockIdx.x;
  int f0 = 32 * (c >> 4) + (c & 15), f1 = f0 + 16;
  float4 a = make_float4(0.f, 0.f, 0.f, 0.f);
  for (int r = threadIdx.x; r < AGG_BLOCKS; r += 256){
    float4 v = pbuf[(size_t)r * 64 + c];
    a.x += v.x; a.y += v.y; a.z += v.z; a.w += v.w;
  }
  __shared__ float4 s[256];
  s[threadIdx.x] = a; __syncthreads();
  for (int off = 128; off; off >>= 1){
    if (threadIdx.x < off){
      float4 o = s[threadIdx.x + off];
      s[threadIdx.x].x += o.x; s[threadIdx.x].y += o.y;
      s[threadIdx.x].z += o.z; s[threadIdx.x].w += o.w;
    }
    __syncthreads();
  }
  if (threadIdx.x == 0){
    float4 t = s[0];
    float inv_n = 1.f / (float)N_;
    float mean0 = t.x * inv_n, mean1 = t.y * inv_n;
    float var0 = fmaxf(t.z * inv_n - mean0 * mean0, 0.f);
    float var1 = fmaxf(t.w * inv_n - mean1 * mean1, 0.f);
    float sc0 = g[f0] * rsqrtf(var0 + EPS_);
    float sc1 = g[f1] * rsqrtf(var1 + EPS_);
    ss[f0] = sc0; ss[f1] = sc1;
    ss[128 + f0] = be[f0] - mean0 * sc0;
    ss[128 + f1] = be[f1] - mean1 * sc1;
  }
}

// ---------------- pool ----------------
__global__ void k_pool2(const unsigned* __restrict__ xn, const int* __restrict__ gs,
                        const float* __restrict__ ss, unsigned* __restrict__ pooled){
  int g = blockIdx.x, f = threadIdx.x & 127, half = threadIdx.x >> 7;
  int idx = ((f >> 5) << 4) | (f & 15);
  int hi = (f >> 4) & 1;
  int s = gs[g], e = gs[g + 1];
  float sc = ss[f], sh = ss[128 + f];
  float a = 0.f;
  for (int n = s + half; n < e; n += 2){
    unsigned u = xn[(size_t)n * 64 + idx];
    float v = hi ? bfhi(u) : bflo(u);
    a += fmaxf(v * sc + sh, 0.f);
  }
  __shared__ float red[256];
  red[threadIdx.x] = a; __syncthreads();
  if (half == 0 && hi == 0){
    float vlo = red[f] + red[f + 128];
    float vhi = red[f + 16] + red[f + 16 + 128];
    pooled[(size_t)g * 64 + idx] = (unsigned)f2bf(vlo) | ((unsigned)f2bf(vhi) << 16);
  }
}

// ---------------- MFMA MLP GEMM ----------------
template<int K, bool RELU, bool OUTF32>
__global__ __launch_bounds__(256) void k_gemm_mfma(const unsigned* __restrict__ A,
                                                   const short* __restrict__ Wt,
                                                   const float* __restrict__ bias,
                                                   void* __restrict__ Cout, int Ncols){
  constexpr int KT = K >> 5;
  int lane = threadIdx.x & 63, wid = threadIdx.x >> 6;
  int cl = lane & 15, g = lane >> 4;
  int row0 = blockIdx.y * 64 + wid * 16;
  int cb = blockIdx.x;
  int arow = row0 + cl;
  const uint4* Ar = (const uint4*)(A + (size_t)arow * (K / 2));

  f32x4 acc[8];
#pragma unroll
  for (int j = 0; j < 8; ++j) acc[j] = (f32x4){0,0,0,0};

  for (int t = 0; t < KT; ++t){
    bf16x8 af = mkaf_u(Ar[t*4 + g]);
#pragma unroll
    for (int j = 0; j < 8; ++j){
      int c = cb * 128 + j * 16 + cl;
      bf16x8 bf = *(const bf16x8*)(Wt + (((size_t)c * KT + t) * 4 + g) * 8);
      acc[j] = __builtin_amdgcn_mfma_f32_16x16x32_bf16(af, bf, acc[j], 0, 0, 0);
    }
  }

  if (OUTF32){
    float* C = (float*)Cout;
#pragma unroll
    for (int r = 0; r < 4; ++r){
      int row = row0 + g * 4 + r;
#pragma unroll
      for (int j = 0; j < 8; ++j){
        int c = cb * 128 + j * 16 + cl;
        float v = acc[j][r] + bias[c];
        if (RELU) v = fmaxf(v, 0.f);
        C[(size_t)row * Ncols + c] = v;
      }
    }
  } else {
    unsigned* C = (unsigned*)Cout;
#pragma unroll
    for (int r = 0; r < 4; ++r){
      int row = row0 + g * 4 + r;
#pragma unroll
      for (int jp = 0; jp < 4; ++jp){
        int clo = cb * 128 + jp * 32 + cl;
        float vlo = acc[2*jp][r] + bias[clo];
        float vhi = acc[2*jp+1][r] + bias[clo + 16];
        if (RELU){ vlo = fmaxf(vlo, 0.f); vhi = fmaxf(vhi, 0.f); }
        C[(size_t)row * (Ncols / 2) + (cb * 4 + jp) * 16 + cl] =
            (unsigned)f2bf(vlo) | ((unsigned)f2bf(vhi) << 16);
      }
    }
  }
}

// ---------------- final layernorm ----------------
__global__ void k_layernorm(const float* __restrict__ xin, const float* __restrict__ g,
                            const float* __restrict__ b, float* __restrict__ out){
  __shared__ float red[8];
  int row = blockIdx.x, tid = threadIdx.x;
  float v0 = xin[(size_t)row*768 + tid];
  float v1 = xin[(size_t)row*768 + tid + 256];
  float v2 = xin[(size_t)row*768 + tid + 512];
  float s = v0 + v1 + v2;
  float q = v0*v0 + v1*v1 + v2*v2;
  s = wave_sum(s); q = wave_sum(q);
  int wid = tid >> 6;
  if ((tid & 63) == 0){ red[wid] = s; red[4 + wid] = q; }
  __syncthreads();
  if (tid == 0){
    float ts = red[0] + red[1] + red[2] + red[3];
    float tq = red[4] + red[5] + red[6] + red[7];
    float mean = ts / 768.f;
    float var = tq / 768.f - mean * mean;
    red[0] = mean; red[1] = rsqrtf(fmaxf(var, 0.f) + EPS_);
  }
  __syncthreads();
  float mean = red[0], inv = red[1];
  out[(size_t)row*768 + tid]       = (v0 - mean) * inv * g[tid]       + b[tid];
  out[(size_t)row*768 + tid + 256] = (v1 - mean) * inv * g[tid + 256] + b[tid + 256];
  out[(size_t)row*768 + tid + 512] = (v2 - mean) * inv * g[tid + 512] + b[tid + 512];
}

extern "C" void kernel_launch(void* const* d_in, const int* in_sizes, int n_in,
                              void* d_out, int out_size, void* d_ws, size_t ws_size,
                              hipStream_t stream){
  const float* x     = (const float*)d_in[0];
  const int*   ei    = (const int*)d_in[1];
  const int*   src   = ei;
  const int*   dst   = ei + E_;
  const int*   batch = (const int*)d_in[2];
  const float* W1 = (const float*)d_in[3];  const float* b1 = (const float*)d_in[4];
  const float* W2 = (const float*)d_in[5];  const float* b2 = (const float*)d_in[6];
  const float* W3 = (const float*)d_in[7];  const float* b3 = (const float*)d_in[8];
  const float* Wa = (const float*)d_in[9];  const float* ba = (const float*)d_in[10];
  const float* a_src = (const float*)d_in[11]; const float* a_dst = (const float*)d_in[12];
  const float* g1 = (const float*)d_in[13]; const float* be1 = (const float*)d_in[14];
  const float* g2 = (const float*)d_in[15]; const float* be2 = (const float*)d_in[16];
  const float* g3 = (const float*)d_in[17]; const float* be3 = (const float*)d_in[18];
  const float* ga = (const float*)d_in[19]; const float* bea = (const float*)d_in[20];
  const float* Wl1 = (const float*)d_in[21]; const float* bl1 = (const float*)d_in[22];
  const float* Wl2 = (const float*)d_in[23]; const float* bl2 = (const float*)d_in[24];
  const float* Wl3 = (const float*)d_in[25]; const float* bl3 = (const float*)d_in[26];
  const float* Wl4 = (const float*)d_in[27]; const float* bl4 = (const float*)d_in[28];
  const float* gln = (const float*)d_in[29]; const float* bln = (const float*)d_in[30];
  float* out = (float*)d_out;

  char* base = (char*)d_ws;
  size_t off = 0;
  auto alloc = [&](size_t bytes)->char*{
    char* p = base + off;
    off += (bytes + 255) & ~(size_t)255;
    return p;
  };
  int*   cnt    = (int*)  alloc((size_t)N_ * 4);
  float* dinv   = (float*)alloc((size_t)N_ * 4);
  int*   ro     = (int*)  alloc((size_t)(N_ + 1) * 4);
  int*   bs     = (int*)  alloc(512 * 4);
  int*   cur    = (int*)  alloc((size_t)N_ * 4);
  int*   csr    = (int*)  alloc((size_t)E_ * 4);
  int*   gstart = (int*)  alloc((size_t)(G_ + 1) * 4);
  float* al     = (float*)alloc((size_t)N_ * 4);
  float* ar     = (float*)alloc((size_t)N_ * 4);
  float* ss     = (float*)alloc(256 * 4);
  float4* pbuf  = (float4*)alloc((size_t)AGG_BLOCKS * 64 * 16);
  short* wt1    = (short*)alloc((size_t)128 * 128 * 2);
  short* wt2    = (short*)alloc((size_t)128 * 128 * 2);
  short* wt3    = (short*)alloc((size_t)128 * 128 * 2);
  short* wta    = (short*)alloc((size_t)128 * 128 * 2);
  short* wtl1   = (short*)alloc((size_t)128 * NHID_ * 2);
  short* wtl2   = (short*)alloc((size_t)NHID_ * NHID_ * 2);
  short* wtl3   = (short*)alloc((size_t)NHID_ * NHID_ * 2);
  short* wtl4   = (short*)alloc((size_t)NHID_ * NOUT_ * 2);
  unsigned* bufH  = (unsigned*)alloc((size_t)N_ * 64 * 4);
  unsigned* bufYb = (unsigned*)alloc((size_t)N_ * 64 * 4);
  unsigned* xresb = (unsigned*)alloc((size_t)N_ * 64 * 4);
  unsigned* pooled= (unsigned*)alloc((size_t)G_ * 64 * 4);
  unsigned* m1b   = (unsigned*)alloc((size_t)G_ * (NHID_/2) * 4);
  unsigned* m2b   = (unsigned*)alloc((size_t)G_ * (NHID_/2) * 4);
  float* m4     = (float*)alloc((size_t)G_ * NOUT_ * 4);
  (void)ws_size; (void)in_sizes; (void)n_in; (void)out_size;

  const int nbE = CDIV(E_, 256), nbN = CDIV(N_, 256);
  const int MMB = CDIV(N_, 128);

  hipMemsetAsync(cnt, 0, (size_t)N_ * 4, stream);
  k_count<<<nbE, 256, 0, stream>>>(dst, cnt);
  k_scan1<<<nbN, 256, 0, stream>>>(cnt, ro, bs, dinv);
  k_scan2<<<1, 512, 0, stream>>>(bs, nbN);
  k_scan3<<<CDIV(N_ + 1, 256), 256, 0, stream>>>(ro, bs);
  hipMemsetAsync(cur, 0, (size_t)N_ * 4, stream);
  k_fill<<<nbE, 256, 0, stream>>>(src, dst, ro, cur, csr);
  k_bounds<<<CDIV(G_ + 1, 256), 256, 0, stream>>>(batch, gstart);

  {
    WprepArgs a;
    const float* Ws[8] = {W1, W2, W3, Wa, Wl1, Wl2, Wl3, Wl4};
    short* Wts[8] = {wt1, wt2, wt3, wta, wtl1, wtl2, wtl3, wtl4};
    int Ks[8] = {128,128,128,128, 128, NHID_, NHID_, NHID_};
    int Ns[8] = {128,128,128,128, NHID_, NHID_, NHID_, NOUT_};
    int run = 0;
    for (int m = 0; m < 8; ++m){
      a.W[m] = Ws[m]; a.Wt[m] = Wts[m]; a.K[m] = Ks[m]; a.N[m] = Ns[m];
      a.ofs[m] = run;
      run += Ns[m] * (Ks[m] >> 5) * 4;
    }
    a.ofs[8] = run;
    k_wprep_all<<<CDIV(run, 256), 256, 0, stream>>>(a);
  }

  // L1
  k_mm_mfma<false,false><<<MMB, 256, 0, stream>>>(x, wt1, bufH, nullptr, nullptr, nullptr,
                                                  dinv, nullptr, nullptr, nullptr, nullptr);
  k_gcn_agg2<<<AGG_BLOCKS, 256, 0, stream>>>(bufH, ro, csr, dinv, b1, bufYb, pbuf);
  k_bn_reduce<<<64, 256, 0, stream>>>(pbuf, g1, be1, ss);
  // L2
  k_mm_mfma<true,false><<<MMB, 256, 0, stream>>>(bufYb, wt2, bufH, ss, x, xresb,
                                                 dinv, nullptr, nullptr, nullptr, nullptr);
  k_gcn_agg2<<<AGG_BLOCKS, 256, 0, stream>>>(bufH, ro, csr, dinv, b2, bufYb, pbuf);
  k_bn_reduce<<<64, 256, 0, stream>>>(pbuf, g2, be2, ss);
  // L3 (in-place residual is safe unsplit: each row read+written by its own wave)
  k_mm_mfma<true,true><<<MMB, 256, 0, stream>>>(bufYb, wt3, bufH, ss, xresb, xresb,
                                                dinv, nullptr, nullptr, nullptr, nullptr);
  k_gcn_agg2<<<AGG_BLOCKS, 256, 0, stream>>>(bufH, ro, csr, dinv, b3, bufYb, pbuf);
  k_bn_reduce<<<64, 256, 0, stream>>>(pbuf, g3, be3, ss);
  // GAT
  k_mm_mfma<true,true><<<MMB, 256, 0, stream>>>(bufYb, wta, bufH, ss, xresb, nullptr,
                                                nullptr, a_src, a_dst, al, ar);
  k_gat_agg2<<<AGG_BLOCKS, 256, 0, stream>>>(bufH, ro, csr, al, ar, ba, bufYb, pbuf);
  k_bn_reduce<<<64, 256, 0, stream>>>(pbuf, ga, bea, ss);
  // pool
  k_pool2<<<G_, 256, 0, stream>>>(bufYb, gstart, ss, pooled);
  // MLP via MFMA
  k_gemm_mfma<128, true, false><<<dim3(NHID_/128, G_/64), 256, 0, stream>>>(pooled, wtl1, bl1, m1b, NHID_);
  k_gemm_mfma<512, true, false><<<dim3(NHID_/128, G_/64), 256, 0, stream>>>(m1b, wtl2, bl2, m2b, NHID_);
  k_gemm_mfma<512, true, false><<<dim3(NHID_/128, G_/64), 256, 0, stream>>>(m2b, wtl3, bl3, m1b, NHID_);
  k_gemm_mfma<512, false, true><<<dim3(NOUT_/128, G_/64), 256, 0, stream>>>(m1b, wtl4, bl4, m4, NOUT_);
  k_layernorm<<<G_, 256, 0, stream>>>(m4, gln, bln, out);
}

// Round 15
// 526.740 us; speedup vs baseline: 1.0486x; 1.0434x over previous
//
#include <hip/hip_runtime.h>
#include <cstdint>
#include <cstddef>

#define CDIV(a,b) (((a)+(b)-1)/(b))

constexpr int N_ = 100000;
constexpr int E_ = 600000;
constexpr int D_ = 128;
constexpr int G_ = 2048;
constexpr int NHID_ = 512;
constexpr int NOUT_ = 768;
constexpr float EPS_ = 1e-5f;
constexpr int AGG_BLOCKS = 2048;

typedef short bf16x8 __attribute__((ext_vector_type(8)));
typedef float f32x4 __attribute__((ext_vector_type(4)));

__device__ __forceinline__ float wave_sum(float v){
#pragma unroll
  for (int m = 32; m; m >>= 1) v += __shfl_xor(v, m, 64);
  return v;
}
__device__ __forceinline__ float lrelu02(float v){ return v > 0.f ? v : 0.2f * v; }
__device__ __forceinline__ unsigned short f2bf(float f){
  unsigned u = __float_as_uint(f);
  u += 0x7FFF + ((u >> 16) & 1);
  return (unsigned short)(u >> 16);
}
__device__ __forceinline__ float bflo(unsigned u){ return __uint_as_float(u << 16); }
__device__ __forceinline__ float bfhi(unsigned u){ return __uint_as_float(u & 0xFFFF0000u); }

__device__ __forceinline__ float4 unplo(uint4 u){ return make_float4(bflo(u.x), bflo(u.y), bflo(u.z), bflo(u.w)); }
__device__ __forceinline__ float4 unphi(uint4 u){ return make_float4(bfhi(u.x), bfhi(u.y), bfhi(u.z), bfhi(u.w)); }
__device__ __forceinline__ float4 bnrelu4(float4 v, float4 sc, float4 sh){
  return make_float4(fmaxf(v.x*sc.x+sh.x, 0.f), fmaxf(v.y*sc.y+sh.y, 0.f),
                     fmaxf(v.z*sc.z+sh.z, 0.f), fmaxf(v.w*sc.w+sh.w, 0.f));
}
__device__ __forceinline__ float4 add4(float4 a, float4 b){
  return make_float4(a.x+b.x, a.y+b.y, a.z+b.z, a.w+b.w);
}
__device__ __forceinline__ uint4 pk4(float4 lo, float4 hi){
  uint4 u;
  u.x = (unsigned)f2bf(lo.x) | ((unsigned)f2bf(hi.x) << 16);
  u.y = (unsigned)f2bf(lo.y) | ((unsigned)f2bf(hi.y) << 16);
  u.z = (unsigned)f2bf(lo.z) | ((unsigned)f2bf(hi.z) << 16);
  u.w = (unsigned)f2bf(lo.w) | ((unsigned)f2bf(hi.w) << 16);
  return u;
}
__device__ __forceinline__ bf16x8 mkaf(float4 lo, float4 hi){
  bf16x8 a;
  a[0]=(short)f2bf(lo.x); a[1]=(short)f2bf(lo.y); a[2]=(short)f2bf(lo.z); a[3]=(short)f2bf(lo.w);
  a[4]=(short)f2bf(hi.x); a[5]=(short)f2bf(hi.y); a[6]=(short)f2bf(hi.z); a[7]=(short)f2bf(hi.w);
  return a;
}
__device__ __forceinline__ bf16x8 mkaf_u(uint4 u){
  bf16x8 a;
  a[0]=(short)(u.x & 0xFFFF); a[4]=(short)(u.x >> 16);
  a[1]=(short)(u.y & 0xFFFF); a[5]=(short)(u.y >> 16);
  a[2]=(short)(u.z & 0xFFFF); a[6]=(short)(u.z >> 16);
  a[3]=(short)(u.w & 0xFFFF); a[7]=(short)(u.w >> 16);
  return a;
}

// ---------------- CSR build ----------------
__global__ void k_count(const int* __restrict__ dst, int* __restrict__ cnt){
  int e = blockIdx.x * 256 + threadIdx.x;
  if (e < E_) atomicAdd(&cnt[dst[e]], 1);
}

__global__ void k_scan1(const int* __restrict__ cnt, int* __restrict__ ro, int* __restrict__ bs,
                        float* __restrict__ dinv){
  __shared__ int s[256];
  int tid = threadIdx.x;
  int i = blockIdx.x * 256 + tid;
  int v = (i < N_) ? cnt[i] : 0;
  s[tid] = v; __syncthreads();
  for (int off = 1; off < 256; off <<= 1){
    int add = (tid >= off) ? s[tid - off] : 0;
    __syncthreads();
    s[tid] += add;
    __syncthreads();
  }
  if (i < N_){
    ro[i] = s[tid] - v;
    dinv[i] = rsqrtf((float)(v + 1));
  }
  if (tid == 255) bs[blockIdx.x] = s[255];
}

__global__ void k_scan2(int* __restrict__ bs, int nb){
  __shared__ int s[512];
  int t = threadIdx.x;
  int v = (t < nb) ? bs[t] : 0;
  s[t] = v; __syncthreads();
  for (int off = 1; off < 512; off <<= 1){
    int a = (t >= off) ? s[t - off] : 0;
    __syncthreads();
    s[t] += a;
    __syncthreads();
  }
  if (t < nb) bs[t] = s[t] - v;
}

__global__ void k_scan3(int* __restrict__ ro, const int* __restrict__ bs){
  int i = blockIdx.x * 256 + threadIdx.x;
  if (i < N_) ro[i] += bs[i >> 8];
  if (i == N_) ro[N_] = E_;
}

__global__ void k_fill(const int* __restrict__ src, const int* __restrict__ dst,
                       const int* __restrict__ ro, int* __restrict__ cur, int* __restrict__ csr){
  int e = blockIdx.x * 256 + threadIdx.x;
  if (e < E_){
    int d = dst[e];
    int p = atomicAdd(&cur[d], 1);
    csr[ro[d] + p] = src[e];
  }
}

__global__ void k_bounds(const int* __restrict__ batch, int* __restrict__ gs){
  int g = blockIdx.x * 256 + threadIdx.x;
  if (g > G_) return;
  int lo = 0, hi = N_;
  while (lo < hi){ int mid = (lo + hi) >> 1; if (batch[mid] < g) lo = mid + 1; else hi = mid; }
  gs[g] = lo;
}

// ---------------- batched W prep ----------------
struct WprepArgs {
  const float* W[8];
  short* Wt[8];
  int K[8];
  int N[8];
  int ofs[9];
};

__global__ void k_wprep_all(WprepArgs a){
  int i = blockIdx.x * 256 + threadIdx.x;
  if (i >= a.ofs[8]) return;
  int m = 0;
  while (i >= a.ofs[m + 1]) ++m;
  int li = i - a.ofs[m];
  int K = a.K[m], Nn = a.N[m];
  int KT = K >> 5;
  int g = li & 3, t = (li >> 2) % KT, c = li / (KT * 4);
  short* o = a.Wt[m] + (size_t)li * 8;
  const float* W = a.W[m];
#pragma unroll
  for (int j = 0; j < 8; ++j){
    int k = t * 32 + (j >> 2) * 16 + g * 4 + (j & 3);
    o[j] = (short)f2bf(W[(size_t)k * Nn + c]);
  }
}

// ---------------- MFMA node matmul, 2 tiles/wave (measured-best structure) ----------------
template<bool XB, bool RB>
__global__ __launch_bounds__(256) void k_mm_mfma(const void* __restrict__ Xin,
                                                 const short* __restrict__ Wt,
                                                 unsigned* __restrict__ hout,
                                                 const float* __restrict__ ss,
                                                 const void* __restrict__ resin,
                                                 unsigned* __restrict__ xnew,
                                                 const float* __restrict__ prescale,
                                                 const float* __restrict__ asrc,
                                                 const float* __restrict__ adst,
                                                 float* __restrict__ al_out,
                                                 float* __restrict__ ar_out){
  int lane = threadIdx.x & 63, wid = threadIdx.x >> 6;
  int cl = lane & 15, g = lane >> 4;
  int r0a = blockIdx.x * 128 + wid * 16;
  int r0b = r0a + 64;
  int rowa = r0a + cl, rowb = r0b + cl;
  bool va_ = rowa < N_, vb_ = rowb < N_;
  int rma = va_ ? rowa : 0;
  int rmb = vb_ ? rowb : 0;
  bool has_res = resin != nullptr;

  uint4 xua[4], xub[4];
  float4 xfa[8], xfb[8];
  uint4 rua[4], rub[4];
  float4 rfa[8], rfb[8];
  if (XB){
    const uint4* Xa = (const uint4*)((const unsigned*)Xin + (size_t)rma * 64);
    const uint4* Xb = (const uint4*)((const unsigned*)Xin + (size_t)rmb * 64);
#pragma unroll
    for (int t = 0; t < 4; ++t){ xua[t] = Xa[t*4 + g]; xub[t] = Xb[t*4 + g]; }
  } else {
    const float4* Xa = (const float4*)((const float*)Xin + (size_t)rma * 128);
    const float4* Xb = (const float4*)((const float*)Xin + (size_t)rmb * 128);
#pragma unroll
    for (int t = 0; t < 4; ++t){
      xfa[2*t] = Xa[t*8 + g]; xfa[2*t+1] = Xa[t*8 + g + 4];
      xfb[2*t] = Xb[t*8 + g]; xfb[2*t+1] = Xb[t*8 + g + 4];
    }
  }
  if (has_res){
    if (RB){
      const uint4* Ra = (const uint4*)((const unsigned*)resin + (size_t)rma * 64);
      const uint4* Rb = (const uint4*)((const unsigned*)resin + (size_t)rmb * 64);
#pragma unroll
      for (int t = 0; t < 4; ++t){ rua[t] = Ra[t*4 + g]; rub[t] = Rb[t*4 + g]; }
    } else {
      const float4* Ra = (const float4*)((const float*)resin + (size_t)rma * 128);
      const float4* Rb = (const float4*)((const float*)resin + (size_t)rmb * 128);
#pragma unroll
      for (int t = 0; t < 4; ++t){
        rfa[2*t] = Ra[t*8 + g]; rfa[2*t+1] = Ra[t*8 + g + 4];
        rfb[2*t] = Rb[t*8 + g]; rfb[2*t+1] = Rb[t*8 + g + 4];
      }
    }
  }
  __builtin_amdgcn_sched_barrier(0);

  bf16x8 afa[4], afb[4];
#pragma unroll
  for (int t = 0; t < 4; ++t){
    float4 la, ha, lb, hb;
    if (XB){
      la = unplo(xua[t]); ha = unphi(xua[t]);
      lb = unplo(xub[t]); hb = unphi(xub[t]);
    } else {
      la = xfa[2*t]; ha = xfa[2*t+1];
      lb = xfb[2*t]; hb = xfb[2*t+1];
    }
    if (ss){
      int f0 = t * 32 + g * 4;
      float4 sc0 = *(const float4*)&ss[f0],      sh0 = *(const float4*)&ss[128 + f0];
      float4 sc1 = *(const float4*)&ss[f0 + 16], sh1 = *(const float4*)&ss[128 + f0 + 16];
      la = bnrelu4(la, sc0, sh0); ha = bnrelu4(ha, sc1, sh1);
      lb = bnrelu4(lb, sc0, sh0); hb = bnrelu4(hb, sc1, sh1);
      if (has_res){
        if (RB){
          la = add4(la, unplo(rua[t])); ha = add4(ha, unphi(rua[t]));
          lb = add4(lb, unplo(rub[t])); hb = add4(hb, unphi(rub[t]));
        } else {
          la = add4(la, rfa[2*t]); ha = add4(ha, rfa[2*t+1]);
          lb = add4(lb, rfb[2*t]); hb = add4(hb, rfb[2*t+1]);
        }
      }
      if (xnew){
        if (va_) *(uint4*)(xnew + (size_t)rowa * 64 + t*16 + g*4) = pk4(la, ha);
        if (vb_) *(uint4*)(xnew + (size_t)rowb * 64 + t*16 + g*4) = pk4(lb, hb);
      }
    }
    afa[t] = mkaf(la, ha);
    afb[t] = mkaf(lb, hb);
  }

  f32x4 accA[8], accB[8];
#pragma unroll
  for (int j = 0; j < 8; ++j){ accA[j] = (f32x4){0,0,0,0}; accB[j] = (f32x4){0,0,0,0}; }
#pragma unroll
  for (int t = 0; t < 4; ++t){
#pragma unroll
    for (int j = 0; j < 8; ++j){
      int c = j * 16 + cl;
      bf16x8 bf = *(const bf16x8*)(Wt + ((size_t)c * 16 + t * 4 + g) * 8);
      accA[j] = __builtin_amdgcn_mfma_f32_16x16x32_bf16(afa[t], bf, accA[j], 0, 0, 0);
      accB[j] = __builtin_amdgcn_mfma_f32_16x16x32_bf16(afb[t], bf, accB[j], 0, 0, 0);
    }
  }

#pragma unroll
  for (int r = 0; r < 4; ++r){
    int ra = r0a + g * 4 + r;
    if (ra < N_){
      float psc = prescale ? prescale[ra] : 1.f;
#pragma unroll
      for (int jp = 0; jp < 4; ++jp){
        unsigned lo = f2bf(accA[2*jp][r] * psc);
        unsigned hi = f2bf(accA[2*jp+1][r] * psc);
        hout[(size_t)ra * 64 + jp * 16 + cl] = (hi << 16) | lo;
      }
    }
    int rb = r0b + g * 4 + r;
    if (rb < N_){
      float psc = prescale ? prescale[rb] : 1.f;
#pragma unroll
      for (int jp = 0; jp < 4; ++jp){
        unsigned lo = f2bf(accB[2*jp][r] * psc);
        unsigned hi = f2bf(accB[2*jp+1][r] * psc);
        hout[(size_t)rb * 64 + jp * 16 + cl] = (hi << 16) | lo;
      }
    }
  }

  if (al_out){
    float pal[8] = {0,0,0,0,0,0,0,0}, par[8] = {0,0,0,0,0,0,0,0};
#pragma unroll
    for (int j = 0; j < 8; ++j){
      float as_ = asrc[j * 16 + cl], ad_ = adst[j * 16 + cl];
#pragma unroll
      for (int r = 0; r < 4; ++r){
        pal[r]   += accA[j][r] * as_; par[r]   += accA[j][r] * ad_;
        pal[4+r] += accB[j][r] * as_; par[4+r] += accB[j][r] * ad_;
      }
    }
#pragma unroll
    for (int m = 1; m < 16; m <<= 1)
#pragma unroll
      for (int r = 0; r < 8; ++r){
        pal[r] += __shfl_xor(pal[r], m, 64);
        par[r] += __shfl_xor(par[r], m, 64);
      }
    if (cl == 0){
#pragma unroll
      for (int r = 0; r < 4; ++r){
        int ra = r0a + g * 4 + r;
        if (ra < N_){ al_out[ra] = pal[r]; ar_out[ra] = par[r]; }
        int rb = r0b + g * 4 + r;
        if (rb < N_){ al_out[rb] = pal[4+r]; ar_out[rb] = par[4+r]; }
      }
    }
  }
}

// ---------------- GCN aggregate (stats -> pbuf) ----------------
__global__ __launch_bounds__(256) void k_gcn_agg2(const unsigned* __restrict__ hbf, const int* __restrict__ ro,
                          const int* __restrict__ csr, const float* __restrict__ dinv,
                          const float* __restrict__ bias, unsigned* __restrict__ outb,
                          float4* __restrict__ pbuf){
  int wid = threadIdx.x >> 6, lane = threadIdx.x & 63;
  int f0 = 32 * (lane >> 4) + (lane & 15), f1 = f0 + 16;
  float bb0 = bias[f0], bb1 = bias[f1];
  float S0 = 0.f, S1 = 0.f, Q0 = 0.f, Q1 = 0.f;
  for (int node = blockIdx.x * 4 + wid; node < N_; node += AGG_BLOCKS * 4){
    int s0 = ro[node], s1 = ro[node + 1];
    int deg = s1 - s0;
    float di = dinv[node];
    unsigned us = hbf[(size_t)node * 64 + lane];
    float a0 = bflo(us), a1 = bfhi(us);
    if (deg <= 64){
      int sidx = (lane < deg) ? csr[s0 + lane] : 0;
      int j = 0;
      for (; j + 4 <= deg; j += 4){
        int sa = __shfl(sidx, j, 64),   sb = __shfl(sidx, j+1, 64);
        int sc = __shfl(sidx, j+2, 64), sd = __shfl(sidx, j+3, 64);
        unsigned ua = hbf[(size_t)sa*64+lane], ub = hbf[(size_t)sb*64+lane];
        unsigned uc = hbf[(size_t)sc*64+lane], ud = hbf[(size_t)sd*64+lane];
        a0 += bflo(ua) + bflo(ub) + bflo(uc) + bflo(ud);
        a1 += bfhi(ua) + bfhi(ub) + bfhi(uc) + bfhi(ud);
      }
      for (; j < deg; ++j){
        int s = __shfl(sidx, j, 64);
        unsigned u = hbf[(size_t)s*64+lane];
        a0 += bflo(u); a1 += bfhi(u);
      }
    } else {
      for (int base = s0; base < s1; base += 64){
        int c = min(64, s1 - base);
        int sidx = (lane < c) ? csr[base + lane] : 0;
        for (int j = 0; j < c; ++j){
          int s = __shfl(sidx, j, 64);
          unsigned u = hbf[(size_t)s*64+lane];
          a0 += bflo(u); a1 += bfhi(u);
        }
      }
    }
    float o0 = di * a0 + bb0;
    float o1 = di * a1 + bb1;
    outb[(size_t)node * 64 + lane] = (unsigned)f2bf(o0) | ((unsigned)f2bf(o1) << 16);
    S0 += o0; S1 += o1; Q0 += o0*o0; Q1 += o1*o1;
  }
  __shared__ float4 sred[4][64];
  sred[wid][lane] = make_float4(S0, S1, Q0, Q1);
  __syncthreads();
  if (wid == 0){
    float4 t = sred[0][lane];
    float4 u1 = sred[1][lane], u2 = sred[2][lane], u3 = sred[3][lane];
    t.x += u1.x + u2.x + u3.x;
    t.y += u1.y + u2.y + u3.y;
    t.z += u1.z + u2.z + u3.z;
    t.w += u1.w + u2.w + u3.w;
    pbuf[(size_t)blockIdx.x * 64 + lane] = t;
  }
}

// ---------------- GAT aggregate (stats -> pbuf) ----------------
__global__ __launch_bounds__(256) void k_gat_agg2(const unsigned* __restrict__ hbf, const int* __restrict__ ro,
                          const int* __restrict__ csr, const float* __restrict__ al,
                          const float* __restrict__ ar, const float* __restrict__ bias,
                          unsigned* __restrict__ outb, float4* __restrict__ pbuf){
  int wid = threadIdx.x >> 6, lane = threadIdx.x & 63;
  int f0 = 32 * (lane >> 4) + (lane & 15), f1 = f0 + 16;
  float bb0 = bias[f0], bb1 = bias[f1];
  float S0 = 0.f, S1 = 0.f, Q0 = 0.f, Q1 = 0.f;
  for (int node = blockIdx.x * 4 + wid; node < N_; node += AGG_BLOCKS * 4){
    int s0 = ro[node], s1 = ro[node + 1];
    int deg = s1 - s0;
    float ari = ar[node], ali = al[node];
    float pself = __expf(lrelu02(ali + ari));
    unsigned uself = hbf[(size_t)node * 64 + lane];
    float h0 = bflo(uself), h1 = bfhi(uself);
    float a0, a1;
    if (deg <= 64){
      int sidx = 0; float p = 0.f;
      if (lane < deg){ sidx = csr[s0 + lane]; p = __expf(lrelu02(al[sidx] + ari)); }
      float invd = 1.f / (wave_sum(p) + pself);
      float wl = p * invd;
      float wsf = pself * invd;
      a0 = wsf * h0; a1 = wsf * h1;
      int j = 0;
      for (; j + 4 <= deg; j += 4){
        int sa = __shfl(sidx, j, 64),   sb = __shfl(sidx, j+1, 64);
        int sc = __shfl(sidx, j+2, 64), sd = __shfl(sidx, j+3, 64);
        float wa = __shfl(wl, j, 64),   wb = __shfl(wl, j+1, 64);
        float wc = __shfl(wl, j+2, 64), wd = __shfl(wl, j+3, 64);
        unsigned ua = hbf[(size_t)sa*64+lane], ub = hbf[(size_t)sb*64+lane];
        unsigned uc = hbf[(size_t)sc*64+lane], ud = hbf[(size_t)sd*64+lane];
        a0 += wa*bflo(ua) + wb*bflo(ub) + wc*bflo(uc) + wd*bflo(ud);
        a1 += wa*bfhi(ua) + wb*bfhi(ub) + wc*bfhi(uc) + wd*bfhi(ud);
      }
      for (; j < deg; ++j){
        int s = __shfl(sidx, j, 64); float w = __shfl(wl, j, 64);
        unsigned u = hbf[(size_t)s*64+lane];
        a0 += w*bflo(u); a1 += w*bfhi(u);
      }
    } else {
      float denom = pself;
      for (int base = s0; base < s1; base += 64){
        int c = min(64, s1 - base);
        float p = 0.f;
        if (lane < c) p = __expf(lrelu02(al[csr[base + lane]] + ari));
        denom += wave_sum(p);
      }
      float invd = 1.f / denom;
      float wsf = pself * invd;
      a0 = wsf * h0; a1 = wsf * h1;
      for (int base = s0; base < s1; base += 64){
        int c = min(64, s1 - base);
        int sidx = 0; float wl = 0.f;
        if (lane < c){ sidx = csr[base + lane]; wl = __expf(lrelu02(al[sidx] + ari)) * invd; }
        for (int j = 0; j < c; ++j){
          int s = __shfl(sidx, j, 64); float w = __shfl(wl, j, 64);
          unsigned u = hbf[(size_t)s*64+lane];
          a0 += w*bflo(u); a1 += w*bfhi(u);
        }
      }
    }
    float o0 = a0 + bb0, o1 = a1 + bb1;
    outb[(size_t)node * 64 + lane] = (unsigned)f2bf(o0) | ((unsigned)f2bf(o1) << 16);
    S0 += o0; S1 += o1; Q0 += o0*o0; Q1 += o1*o1;
  }
  __shared__ float4 sred[4][64];
  sred[wid][lane] = make_float4(S0, S1, Q0, Q1);
  __syncthreads();
  if (wid == 0){
    float4 t = sred[0][lane];
    float4 u1 = sred[1][lane], u2 = sred[2][lane], u3 = sred[3][lane];
    t.x += u1.x + u2.x + u3.x;
    t.y += u1.y + u2.y + u3.y;
    t.z += u1.z + u2.z + u3.z;
    t.w += u1.w + u2.w + u3.w;
    pbuf[(size_t)blockIdx.x * 64 + lane] = t;
  }
}

// ---------------- BN partial reduce ----------------
__global__ void k_bn_reduce(const float4* __restrict__ pbuf, const float* __restrict__ g,
                            const float* __restrict__ be, float* __restrict__ ss){
  int c = blockIdx.x;
  int f0 = 32 * (c >> 4) + (c & 15), f1 = f0 + 16;
  float4 a = make_float4(0.f, 0.f, 0.f, 0.f);
  for (int r = threadIdx.x; r < AGG_BLOCKS; r += 256){
    float4 v = pbuf[(size_t)r * 64 + c];
    a.x += v.x; a.y += v.y; a.z += v.z; a.w += v.w;
  }
  __shared__ float4 s[256];
  s[threadIdx.x] = a; __syncthreads();
  for (int off = 128; off; off >>= 1){
    if (threadIdx.x < off){
      float4 o = s[threadIdx.x + off];
      s[threadIdx.x].x += o.x; s[threadIdx.x].y += o.y;
      s[threadIdx.x].z += o.z; s[threadIdx.x].w += o.w;
    }
    __syncthreads();
  }
  if (threadIdx.x == 0){
    float4 t = s[0];
    float inv_n = 1.f / (float)N_;
    float mean0 = t.x * inv_n, mean1 = t.y * inv_n;
    float var0 = fmaxf(t.z * inv_n - mean0 * mean0, 0.f);
    float var1 = fmaxf(t.w * inv_n - mean1 * mean1, 0.f);
    float sc0 = g[f0] * rsqrtf(var0 + EPS_);
    float sc1 = g[f1] * rsqrtf(var1 + EPS_);
    ss[f0] = sc0; ss[f1] = sc1;
    ss[128 + f0] = be[f0] - mean0 * sc0;
    ss[128 + f1] = be[f1] - mean1 * sc1;
  }
}

// ---------------- pool ----------------
__global__ void k_pool2(const unsigned* __restrict__ xn, const int* __restrict__ gs,
                        const float* __restrict__ ss, unsigned* __restrict__ pooled){
  int g = blockIdx.x, f = threadIdx.x & 127, half = threadIdx.x >> 7;
  int idx = ((f >> 5) << 4) | (f & 15);
  int hi = (f >> 4) & 1;
  int s = gs[g], e = gs[g + 1];
  float sc = ss[f], sh = ss[128 + f];
  float a = 0.f;
  for (int n = s + half; n < e; n += 2){
    unsigned u = xn[(size_t)n * 64 + idx];
    float v = hi ? bfhi(u) : bflo(u);
    a += fmaxf(v * sc + sh, 0.f);
  }
  __shared__ float red[256];
  red[threadIdx.x] = a; __syncthreads();
  if (half == 0 && hi == 0){
    float vlo = red[f] + red[f + 128];
    float vhi = red[f + 16] + red[f + 16 + 128];
    pooled[(size_t)g * 64 + idx] = (unsigned)f2bf(vlo) | ((unsigned)f2bf(vhi) << 16);
  }
}

// ---------------- MFMA MLP GEMM ----------------
template<int K, bool RELU, bool OUTF32>
__global__ __launch_bounds__(256) void k_gemm_mfma(const unsigned* __restrict__ A,
                                                   const short* __restrict__ Wt,
                                                   const float* __restrict__ bias,
                                                   void* __restrict__ Cout, int Ncols){
  constexpr int KT = K >> 5;
  int lane = threadIdx.x & 63, wid = threadIdx.x >> 6;
  int cl = lane & 15, g = lane >> 4;
  int row0 = blockIdx.y * 64 + wid * 16;
  int cb = blockIdx.x;
  int arow = row0 + cl;
  const uint4* Ar = (const uint4*)(A + (size_t)arow * (K / 2));

  f32x4 acc[8];
#pragma unroll
  for (int j = 0; j < 8; ++j) acc[j] = (f32x4){0,0,0,0};

  for (int t = 0; t < KT; ++t){
    bf16x8 af = mkaf_u(Ar[t*4 + g]);
#pragma unroll
    for (int j = 0; j < 8; ++j){
      int c = cb * 128 + j * 16 + cl;
      bf16x8 bf = *(const bf16x8*)(Wt + (((size_t)c * KT + t) * 4 + g) * 8);
      acc[j] = __builtin_amdgcn_mfma_f32_16x16x32_bf16(af, bf, acc[j], 0, 0, 0);
    }
  }

  if (OUTF32){
    float* C = (float*)Cout;
#pragma unroll
    for (int r = 0; r < 4; ++r){
      int row = row0 + g * 4 + r;
#pragma unroll
      for (int j = 0; j < 8; ++j){
        int c = cb * 128 + j * 16 + cl;
        float v = acc[j][r] + bias[c];
        if (RELU) v = fmaxf(v, 0.f);
        C[(size_t)row * Ncols + c] = v;
      }
    }
  } else {
    unsigned* C = (unsigned*)Cout;
#pragma unroll
    for (int r = 0; r < 4; ++r){
      int row = row0 + g * 4 + r;
#pragma unroll
      for (int jp = 0; jp < 4; ++jp){
        int clo = cb * 128 + jp * 32 + cl;
        float vlo = acc[2*jp][r] + bias[clo];
        float vhi = acc[2*jp+1][r] + bias[clo + 16];
        if (RELU){ vlo = fmaxf(vlo, 0.f); vhi = fmaxf(vhi, 0.f); }
        C[(size_t)row * (Ncols / 2) + (cb * 4 + jp) * 16 + cl] =
            (unsigned)f2bf(vlo) | ((unsigned)f2bf(vhi) << 16);
      }
    }
  }
}

// ---------------- final layernorm ----------------
__global__ void k_layernorm(const float* __restrict__ xin, const float* __restrict__ g,
                            const float* __restrict__ b, float* __restrict__ out){
  __shared__ float red[8];
  int row = blockIdx.x, tid = threadIdx.x;
  float v0 = xin[(size_t)row*768 + tid];
  float v1 = xin[(size_t)row*768 + tid + 256];
  float v2 = xin[(size_t)row*768 + tid + 512];
  float s = v0 + v1 + v2;
  float q = v0*v0 + v1*v1 + v2*v2;
  s = wave_sum(s); q = wave_sum(q);
  int wid = tid >> 6;
  if ((tid & 63) == 0){ red[wid] = s; red[4 + wid] = q; }
  __syncthreads();
  if (tid == 0){
    float ts = red[0] + red[1] + red[2] + red[3];
    float tq = red[4] + red[5] + red[6] + red[7];
    float mean = ts / 768.f;
    float var = tq / 768.f - mean * mean;
    red[0] = mean; red[1] = rsqrtf(fmaxf(var, 0.f) + EPS_);
  }
  __syncthreads();
  float mean = red[0], inv = red[1];
  out[(size_t)row*768 + tid]       = (v0 - mean) * inv * g[tid]       + b[tid];
  out[(size_t)row*768 + tid + 256] = (v1 - mean) * inv * g[tid + 256] + b[tid + 256];
  out[(size_t)row*768 + tid + 512] = (v2 - mean) * inv * g[tid + 512] + b[tid + 512];
}

extern "C" void kernel_launch(void* const* d_in, const int* in_sizes, int n_in,
                              void* d_out, int out_size, void* d_ws, size_t ws_size,
                              hipStream_t stream){
  const float* x     = (const float*)d_in[0];
  const int*   ei    = (const int*)d_in[1];
  const int*   src   = ei;
  const int*   dst   = ei + E_;
  const int*   batch = (const int*)d_in[2];
  const float* W1 = (const float*)d_in[3];  const float* b1 = (const float*)d_in[4];
  const float* W2 = (const float*)d_in[5];  const float* b2 = (const float*)d_in[6];
  const float* W3 = (const float*)d_in[7];  const float* b3 = (const float*)d_in[8];
  const float* Wa = (const float*)d_in[9];  const float* ba = (const float*)d_in[10];
  const float* a_src = (const float*)d_in[11]; const float* a_dst = (const float*)d_in[12];
  const float* g1 = (const float*)d_in[13]; const float* be1 = (const float*)d_in[14];
  const float* g2 = (const float*)d_in[15]; const float* be2 = (const float*)d_in[16];
  const float* g3 = (const float*)d_in[17]; const float* be3 = (const float*)d_in[18];
  const float* ga = (const float*)d_in[19]; const float* bea = (const float*)d_in[20];
  const float* Wl1 = (const float*)d_in[21]; const float* bl1 = (const float*)d_in[22];
  const float* Wl2 = (const float*)d_in[23]; const float* bl2 = (const float*)d_in[24];
  const float* Wl3 = (const float*)d_in[25]; const float* bl3 = (const float*)d_in[26];
  const float* Wl4 = (const float*)d_in[27]; const float* bl4 = (const float*)d_in[28];
  const float* gln = (const float*)d_in[29]; const float* bln = (const float*)d_in[30];
  float* out = (float*)d_out;

  char* base = (char*)d_ws;
  size_t off = 0;
  auto alloc = [&](size_t bytes)->char*{
    char* p = base + off;
    off += (bytes + 255) & ~(size_t)255;
    return p;
  };
  int*   cnt    = (int*)  alloc((size_t)N_ * 4);
  float* dinv   = (float*)alloc((size_t)N_ * 4);
  int*   ro     = (int*)  alloc((size_t)(N_ + 1) * 4);
  int*   bs     = (int*)  alloc(512 * 4);
  int*   cur    = (int*)  alloc((size_t)N_ * 4);
  int*   csr    = (int*)  alloc((size_t)E_ * 4);
  int*   gstart = (int*)  alloc((size_t)(G_ + 1) * 4);
  float* al     = (float*)alloc((size_t)N_ * 4);
  float* ar     = (float*)alloc((size_t)N_ * 4);
  float* ss     = (float*)alloc(256 * 4);
  float4* pbuf  = (float4*)alloc((size_t)AGG_BLOCKS * 64 * 16);
  short* wt1    = (short*)alloc((size_t)128 * 128 * 2);
  short* wt2    = (short*)alloc((size_t)128 * 128 * 2);
  short* wt3    = (short*)alloc((size_t)128 * 128 * 2);
  short* wta    = (short*)alloc((size_t)128 * 128 * 2);
  short* wtl1   = (short*)alloc((size_t)128 * NHID_ * 2);
  short* wtl2   = (short*)alloc((size_t)NHID_ * NHID_ * 2);
  short* wtl3   = (short*)alloc((size_t)NHID_ * NHID_ * 2);
  short* wtl4   = (short*)alloc((size_t)NHID_ * NOUT_ * 2);
  unsigned* bufH  = (unsigned*)alloc((size_t)N_ * 64 * 4);
  unsigned* bufYb = (unsigned*)alloc((size_t)N_ * 64 * 4);
  unsigned* xresb = (unsigned*)alloc((size_t)N_ * 64 * 4);
  unsigned* pooled= (unsigned*)alloc((size_t)G_ * 64 * 4);
  unsigned* m1b   = (unsigned*)alloc((size_t)G_ * (NHID_/2) * 4);
  unsigned* m2b   = (unsigned*)alloc((size_t)G_ * (NHID_/2) * 4);
  float* m4     = (float*)alloc((size_t)G_ * NOUT_ * 4);
  (void)ws_size; (void)in_sizes; (void)n_in; (void)out_size;

  const int nbE = CDIV(E_, 256), nbN = CDIV(N_, 256);
  const int MMB = CDIV(N_, 128);

  hipMemsetAsync(cnt, 0, (size_t)N_ * 4, stream);
  k_count<<<nbE, 256, 0, stream>>>(dst, cnt);
  k_scan1<<<nbN, 256, 0, stream>>>(cnt, ro, bs, dinv);
  k_scan2<<<1, 512, 0, stream>>>(bs, nbN);
  k_scan3<<<CDIV(N_ + 1, 256), 256, 0, stream>>>(ro, bs);
  hipMemsetAsync(cur, 0, (size_t)N_ * 4, stream);
  k_fill<<<nbE, 256, 0, stream>>>(src, dst, ro, cur, csr);
  k_bounds<<<CDIV(G_ + 1, 256), 256, 0, stream>>>(batch, gstart);

  {
    WprepArgs a;
    const float* Ws[8] = {W1, W2, W3, Wa, Wl1, Wl2, Wl3, Wl4};
    short* Wts[8] = {wt1, wt2, wt3, wta, wtl1, wtl2, wtl3, wtl4};
    int Ks[8] = {128,128,128,128, 128, NHID_, NHID_, NHID_};
    int Ns[8] = {128,128,128,128, NHID_, NHID_, NHID_, NOUT_};
    int run = 0;
    for (int m = 0; m < 8; ++m){
      a.W[m] = Ws[m]; a.Wt[m] = Wts[m]; a.K[m] = Ks[m]; a.N[m] = Ns[m];
      a.ofs[m] = run;
      run += Ns[m] * (Ks[m] >> 5) * 4;
    }
    a.ofs[8] = run;
    k_wprep_all<<<CDIV(run, 256), 256, 0, stream>>>(a);
  }

  // L1
  k_mm_mfma<false,false><<<MMB, 256, 0, stream>>>(x, wt1, bufH, nullptr, nullptr, nullptr,
                                                  dinv, nullptr, nullptr, nullptr, nullptr);
  k_gcn_agg2<<<AGG_BLOCKS, 256, 0, stream>>>(bufH, ro, csr, dinv, b1, bufYb, pbuf);
  k_bn_reduce<<<64, 256, 0, stream>>>(pbuf, g1, be1, ss);
  // L2
  k_mm_mfma<true,false><<<MMB, 256, 0, stream>>>(bufYb, wt2, bufH, ss, x, xresb,
                                                 dinv, nullptr, nullptr, nullptr, nullptr);
  k_gcn_agg2<<<AGG_BLOCKS, 256, 0, stream>>>(bufH, ro, csr, dinv, b2, bufYb, pbuf);
  k_bn_reduce<<<64, 256, 0, stream>>>(pbuf, g2, be2, ss);
  // L3 (in-place residual safe: each row read+written by its own wave)
  k_mm_mfma<true,true><<<MMB, 256, 0, stream>>>(bufYb, wt3, bufH, ss, xresb, xresb,
                                                dinv, nullptr, nullptr, nullptr, nullptr);
  k_gcn_agg2<<<AGG_BLOCKS, 256, 0, stream>>>(bufH, ro, csr, dinv, b3, bufYb, pbuf);
  k_bn_reduce<<<64, 256, 0, stream>>>(pbuf, g3, be3, ss);
  // GAT
  k_mm_mfma<true,true><<<MMB, 256, 0, stream>>>(bufYb, wta, bufH, ss, xresb, nullptr,
                                                nullptr, a_src, a_dst, al, ar);
  k_gat_agg2<<<AGG_BLOCKS, 256, 0, stream>>>(bufH, ro, csr, al, ar, ba, bufYb, pbuf);
  k_bn_reduce<<<64, 256, 0, stream>>>(pbuf, ga, bea, ss);
  // pool
  k_pool2<<<G_, 256, 0, stream>>>(bufYb, gstart, ss, pooled);
  // MLP via MFMA
  k_gemm_mfma<128, true, false><<<dim3(NHID_/128, G_/64), 256, 0, stream>>>(pooled, wtl1, bl1, m1b, NHID_);
  k_gemm_mfma<512, true, false><<<dim3(NHID_/128, G_/64), 256, 0, stream>>>(m1b, wtl2, bl2, m2b, NHID_);
  k_gemm_mfma<512, true, false><<<dim3(NHID_/128, G_/64), 256, 0, stream>>>(m2b, wtl3, bl3, m1b, NHID_);
  k_gemm_mfma<512, false, true><<<dim3(NOUT_/128, G_/64), 256, 0, stream>>>(m1b, wtl4, bl4, m4, NOUT_);
  k_layernorm<<<G_, 256, 0, stream>>>(m4, gln, bln, out);
}